// Round 12
// baseline (213.943 us; speedup 1.0000x reference)
//
#include <hip/hip_runtime.h>
#include <math.h>

// SpectrumHead: rfft2(512x512) magnitude -> radial/angular histogram -> linear proj.
// B=64, C=3, H=512, W=512, W2=257, K_BINS=16, O_BINS=8, proj=64.
//
// Three-step 512 = 8x8x8 register FFT in WAVE-PRIVATE LDS segments (same-wave
// LDS ops are in-order on CDNA -> no barriers between transpose phases; only
// sched_barrier(0) pins compiler order). Swizzle PH(i) = i ^ 9*(i>>6&7), written
// in folded form (C ^ 9q) + 64q. All FFT phases at the wave64 LDS bank floor.
//
// F intermediate stored TRANSPOSED + bf16-packed: FT[ch_img][j][i] (uint32 per
// complex) -> pass2 column loads are contiguous 2KB runs, no cross-wave staging.
//
// Pass 0: transposed bin table binsT[j][i].
// Pass 1: TPB 1024 (16 waves = 16 row-pairs). Wave-private FFT + Hermitian
//         unpack + bf16 pack; ONE barrier; transposed write-out (128B i-runs).
// Pass 2: TPB 192 = 3 channel-waves x ONE column. Each wave: 1 FFT, per-channel
//         mags to plain LDS magbuf[c][row] (no atomics; lane-bijective rows).
//         One barrier; 192 threads cooperatively log1p+hist (512 entries);
//         fold 128 bins -> 24 per-column partials. 12.9 KB LDS -> 10 blocks/CU.
// Pass 3: reduce 257 column-partials per batch, normalize, h @ W.T + b.
//
// Twiddles: no LDS tables; per-thread sincosf + chained powers.
//
// LAUNCH BOUNDS CALIBRATION (empirical, this toolchain): reported VGPR cap
// ~= 256/arg2 (r3:3->80, r4/6:6->40, r7:8->32, r8:4->56 no-spill). arg2=4 ->
// cap 64; FFT kernels need ~40-50.

#define TPB0 256
#define TPB1 1024
#define TPB2 192
#define W2 257
#define CS 529             // pass1 per-wave segment stride, float2 units
#define CSU (2*CS)         // same stride in uint units (1058)
#define CSB 513            // pass2 per-wave segment stride, uint units
#define FTS 512            // FT row stride in uints (2KB rows, line-aligned)
#define PI_F 3.14159265358979323846f
#define TWO_PI_F 6.28318530717958647692f
#define SB() __builtin_amdgcn_sched_barrier(0)
#define PH(i) ((i) ^ ((((i) >> 6) & 7) * 9))

// exp(-2*pi*i*k/32), k = 0..15
static constexpr float TW32_RE[16] = {
   1.0f,          0.98078528f,  0.92387953f,  0.83146961f,
   0.70710678f,   0.55557023f,  0.38268343f,  0.19509032f,
   0.0f,         -0.19509032f, -0.38268343f, -0.55557023f,
  -0.70710678f,  -0.83146961f, -0.92387953f, -0.98078528f };
static constexpr float TW32_IM[16] = {
  -0.0f,         -0.19509032f, -0.38268343f, -0.55557023f,
  -0.70710678f,  -0.83146961f, -0.92387953f, -0.98078528f,
  -1.0f,         -0.98078528f, -0.92387953f, -0.83146961f,
  -0.70710678f,  -0.55557023f, -0.38268343f, -0.19509032f };

static constexpr int BR3[8] = {0,4,2,6,1,5,3,7};

__device__ __forceinline__ float2 cmulf(float2 a, float2 b) {
  return make_float2(a.x*b.x - a.y*b.y, a.x*b.y + a.y*b.x);
}
__device__ __forceinline__ unsigned bfpack(float2 v) {
  unsigned a = __float_as_uint(v.x) >> 16;
  unsigned b = __float_as_uint(v.y) & 0xFFFF0000u;
  return b | a;
}
__device__ __forceinline__ float2 bfunpack(unsigned p) {
  return make_float2(__uint_as_float(p << 16), __uint_as_float(p & 0xFFFF0000u));
}

// In-register DIT FFT8, twiddles from TW32. Input bit-rev permuted; output
// natural. Fully unrolled -> VGPRs.
template <int LOGN>
__device__ __forceinline__ void fft_reg(float2* z) {
  const int N = 1 << LOGN;
  #pragma unroll
  for (int s = 0; s < LOGN; ++s) {
    const int h = 1 << s;
    #pragma unroll
    for (int g0 = 0; g0 < N; g0 += 2 * h) {
      #pragma unroll
      for (int jj = 0; jj < h; ++jj) {
        const int k = jj << (4 - s);
        const float wr = TW32_RE[k], wi = TW32_IM[k];
        float2 a = z[g0 + jj];
        float2 b = z[g0 + jj + h];
        float tr = b.x * wr - b.y * wi;
        float ti = b.x * wi + b.y * wr;
        z[g0 + jj]     = make_float2(a.x + tr, a.y + ti);
        z[g0 + jj + h] = make_float2(a.x - tr, a.y - ti);
      }
    }
  }
}

// Apply chained twiddle powers: z[k] *= base^k, k = 1..7.
__device__ __forceinline__ void twiddle_chain(float2* z, float2 base) {
  float2 wk = base;
  #pragma unroll
  for (int k = 1; k < 8; ++k) {
    z[k] = cmulf(z[k], wk);
    if (k < 7) wk = cmulf(wk, base);
  }
}

__device__ __forceinline__ void get_bins(int i, int j, int& rb, int& ob) {
  float yy = -1.0f + (float)i * (2.0f / 511.0f);
  float xx = (float)j * (1.0f / 256.0f);
  float rr = sqrtf(yy * yy + xx * xx);
  rr = fminf(rr, 1.0f - 1e-8f);
  float th = atan2f(yy, xx + 1e-9f) + 1.57079632679489662f;
  rb = (int)(rr * 16.0f);
  rb = rb < 0 ? 0 : (rb > 15 ? 15 : rb);
  ob = (int)((th / PI_F) * 8.0f);
  ob = ob < 0 ? 0 : (ob > 7 ? 7 : ob);
}

// Pass 0: TRANSPOSED bin table binsT[j][i] = rb | ob<<4. blockIdx.x = j.
__global__ __launch_bounds__(TPB0) void pass0_kernel(unsigned char* __restrict__ binsT) {
  int j = blockIdx.x;           // 0..256
  #pragma unroll
  for (int e = 0; e < 2; e++) {
    int i = threadIdx.x + e * 256;
    int rb, ob;
    get_bins(i, j, rb, ob);
    binsT[(size_t)j * 512 + i] = (unsigned char)(rb | (ob << 4));
  }
}

// Pass 1: blockIdx.x = ic_local*16 + segblk. Wave wv = row-pair
// rp = segblk*16 + wv (rows 2rp, 2rp+1 packed as one complex 512-pt FFT).
// Output: FT[ic_local][j][i] bf16-packed, i-chunk [segblk*32, +32).
__global__ __launch_bounds__(TPB1, 4) void pass1_kernel(
    const float* __restrict__ x, unsigned* __restrict__ FT, int ic0) {
  __shared__ float2 xbuf[16 * CS];       // 67.7 KB: 16 wave-private segments
  int t = threadIdx.x;
  int segblk = blockIdx.x & 15;
  int ic_local = blockIdx.x >> 4;
  int wv = t >> 6;
  int u = t & 63;
  int rp = segblk * 16 + wv;
  const float* row0 = x + (((size_t)(ic0 + ic_local)) * 512 + (size_t)rp * 2) * 512;
  const float* row1 = row0 + 512;
  float2* seg = xbuf + wv * CS;
  unsigned* useg = (unsigned*)xbuf + wv * CSU;

  const int ul = u & 7, wq = u >> 3;
  const int x9 = 9 * wq, b64 = 64 * wq;

  float2 w1, w64;
  { float sn, cs;
    sincosf(-TWO_PI_F * (float)u * (1.0f / 512.0f), &sn, &cs);  w1  = make_float2(cs, sn);
    sincosf(-TWO_PI_F * (float)ul * (1.0f / 64.0f), &sn, &cs);  w64 = make_float2(cs, sn); }

  // step 1: FFT8 over m, twiddle W512^(u*k3) via chain
  float2 z[8];
  #pragma unroll
  for (int m = 0; m < 8; ++m)
    z[BR3[m]] = make_float2(row0[u + 64 * m], row1[u + 64 * m]);
  fft_reg<3>(z);
  twiddle_chain(z, w1);
  SB();
  #pragma unroll
  for (int k3 = 0; k3 < 8; ++k3) seg[(u ^ (9 * k3)) + 64 * k3] = z[k3];   // L1[k3][u]
  SB();
  // step 2: FFT8 over g2, twiddle W64^(ul*K2) via chain
  #pragma unroll
  for (int g2 = 0; g2 < 8; ++g2) z[BR3[g2]] = seg[((ul + 8 * g2) ^ x9) + b64];
  fft_reg<3>(z);
  twiddle_chain(z, w64);
  SB();
  #pragma unroll
  for (int K2 = 0; K2 < 8; ++K2) seg[((K2 * 8 + ul) ^ x9) + b64] = z[K2]; // L2
  SB();
  // step 3: FFT8 over g1 -> Z[wq + 8ul + 64K1]
  #pragma unroll
  for (int gg = 0; gg < 8; ++gg) z[BR3[gg]] = seg[((ul * 8 + gg) ^ x9) + b64];
  fft_reg<3>(z);
  SB();
  #pragma unroll
  for (int K1 = 0; K1 < 8; ++K1)
    seg[((wq + 8 * ul) ^ (9 * K1)) + 64 * K1] = z[K1];                    // Z natural, swizzled
  SB();
  // Hermitian unpack (fp32) + bf16 pack; stash as uints in own segment.
  unsigned p0[4], p1[4];
  #pragma unroll
  for (int e = 0; e < 4; ++e) {
    int k = u + 64 * e;
    int km = (512 - k) & 511;
    float2 zk = seg[PH(k)];
    float2 zm = seg[PH(km)];
    p0[e] = bfpack(make_float2(0.5f * (zk.x + zm.x),  0.5f * (zk.y - zm.y)));
    p1[e] = bfpack(make_float2(0.5f * (zk.y + zm.y), -0.5f * (zk.x - zm.x)));
  }
  unsigned p0n = 0, p1n = 0;
  if (u == 0) {
    float2 zk = seg[PH(256)];            // Nyquist (self-paired)
    p0n = bfpack(make_float2(zk.x, 0.0f));
    p1n = bfpack(make_float2(zk.y, 0.0f));
  }
  SB();
  #pragma unroll
  for (int e = 0; e < 4; ++e) {
    int k = u + 64 * e;
    useg[k] = p0[e];                     // row 2rp   spectrum at [k]
    useg[257 + k] = p1[e];               // row 2rp+1 spectrum at [257+k]
  }
  if (u == 0) { useg[256] = p0n; useg[513] = p1n; }
  __syncthreads();

  // transposed write-out: for each j, 32 consecutive i (128B run).
  unsigned* FTc = FT + (size_t)ic_local * (W2 * FTS);
  int i0 = segblk * 32;
  const unsigned* xb = (const unsigned*)xbuf;
  #pragma unroll
  for (int it = 0; it < 9; ++it) {
    int idx = t + TPB1 * it;
    if (idx < W2 * 32) {
      int j = idx >> 5;
      int il = idx & 31;                 // i_local = 2*pair + hi
      unsigned v = xb[(il >> 1) * CSU + (il & 1) * 257 + j];
      FTc[(size_t)j * FTS + i0 + il] = v;
    }
  }
}

// Pass 2: blockIdx.x = b_local*W2 + j. Block = 3 channel-waves x ONE column.
// Wave c: contiguous 2KB load of FT[ch=c][j][:], wave-private bf16 FFT, store
// per-channel |X| to magbuf[c][row] (plain LDS; rows lane-bijective). Then one
// barrier; 192 threads do mag-sum -> log1p -> 128-bin hist; fold to 24.
__global__ __launch_bounds__(TPB2, 4) void pass2_kernel(
    const unsigned* __restrict__ FT, const unsigned char* __restrict__ binsT,
    float* __restrict__ partial, int b0) {
  __shared__ unsigned xseg[3 * CSB];     // 6.2 KB: 3 wave-private segments
  __shared__ float magbuf[3][512];       // 6 KB per-channel magnitudes
  __shared__ float hist[128];            // combined bins: rb + 16*ob
  int t = threadIdx.x;
  int j = blockIdx.x % W2;
  int b_local = blockIdx.x / W2;
  int c = t >> 6;                        // channel wave (0..2)
  int u = t & 63;
  unsigned* seg = xseg + c * CSB;
  const int ul = u & 7, wq = u >> 3;
  const int x9 = 9 * wq, b64 = 64 * wq;

  if (t < 128) hist[t] = 0.0f;

  float2 w1, w64;
  { float sn, cs;
    sincosf(-TWO_PI_F * (float)u * (1.0f / 512.0f), &sn, &cs);  w1  = make_float2(cs, sn);
    sincosf(-TWO_PI_F * (float)ul * (1.0f / 64.0f), &sn, &cs);  w64 = make_float2(cs, sn); }

  const unsigned* col = FT + ((size_t)(b_local * 3 + c) * W2 + j) * FTS;
  float2 z[8];
  #pragma unroll
  for (int m = 0; m < 8; ++m) z[BR3[m]] = bfunpack(col[u + 64 * m]);
  fft_reg<3>(z);
  twiddle_chain(z, w1);
  SB();
  #pragma unroll
  for (int k3 = 0; k3 < 8; ++k3) seg[(u ^ (9 * k3)) + 64 * k3] = bfpack(z[k3]);
  SB();
  #pragma unroll
  for (int g2 = 0; g2 < 8; ++g2) z[BR3[g2]] = bfunpack(seg[((ul + 8 * g2) ^ x9) + b64]);
  fft_reg<3>(z);
  twiddle_chain(z, w64);
  SB();
  #pragma unroll
  for (int K2 = 0; K2 < 8; ++K2) seg[((K2 * 8 + ul) ^ x9) + b64] = bfpack(z[K2]);
  SB();
  #pragma unroll
  for (int gg = 0; gg < 8; ++gg) z[BR3[gg]] = bfunpack(seg[((ul * 8 + gg) ^ x9) + b64]);
  fft_reg<3>(z);
  #pragma unroll
  for (int K1 = 0; K1 < 8; ++K1) {
    int row = wq + 8 * ul + 64 * K1;     // lane-bijective per K1 -> no collisions
    magbuf[c][row] = sqrtf(z[K1].x * z[K1].x + z[K1].y * z[K1].y);
  }
  __syncthreads();

  // cooperative: sum channels, log1p, histogram (512 entries / 192 threads)
  const unsigned char* bj = binsT + (size_t)j * 512;
  for (int row = t; row < 512; row += TPB2) {
    float m = magbuf[0][row] + magbuf[1][row] + magbuf[2][row];
    int code = bj[row];
    // scale: ortho (1/512) * channel mean (1/3) = 1/1536
    atomicAdd(&hist[code], log1pf(m * (1.0f / 1536.0f)));
  }
  __syncthreads();

  // fold 128 combined bins -> 16 radial + 8 angular per-column partials
  int b = b0 + b_local;
  if (t < 16) {
    float s = 0.0f;
    #pragma unroll
    for (int ob = 0; ob < 8; ++ob) s += hist[t + 16 * ob];
    partial[((size_t)b * W2 + j) * 24 + t] = s;
  } else if (t < 24) {
    float s = 0.0f;
    int ob = t - 16;
    #pragma unroll
    for (int rb = 0; rb < 16; ++rb) s += hist[rb + 16 * ob];
    partial[((size_t)b * W2 + j) * 24 + t] = s;
  }
}

// Pass 3: one block per batch. Reduce W2 column-partials, normalize, project.
__global__ __launch_bounds__(TPB0) void pass3_kernel(
    const float* __restrict__ partial, const float* __restrict__ W,
    const float* __restrict__ bias, float* __restrict__ out) {
  __shared__ float h[24];
  __shared__ float hn[24];
  int b = blockIdx.x;
  int t = threadIdx.x;
  if (t < 24) {
    float s = 0.0f;
    for (int jc = 0; jc < W2; jc++)
      s += partial[((size_t)b * W2 + jc) * 24 + t];
    h[t] = s;
  }
  __syncthreads();
  if (t == 0) {
    float rs = 0.0f, as = 0.0f;
    for (int k = 0; k < 16; k++) rs += h[k];
    for (int k = 16; k < 24; k++) as += h[k];
    for (int k = 0; k < 16; k++) hn[k] = h[k] / (rs + 1e-6f);
    for (int k = 16; k < 24; k++) hn[k] = h[k] / (as + 1e-6f);
  }
  __syncthreads();
  if (t < 64) {
    float acc = bias[t];
    #pragma unroll
    for (int k = 0; k < 24; k++) acc += hn[k] * W[t * 24 + k];
    out[b * 64 + t] = acc;
  }
}

extern "C" void kernel_launch(void* const* d_in, const int* in_sizes, int n_in,
                              void* d_out, int out_size, void* d_ws, size_t ws_size,
                              hipStream_t stream) {
  const float* x    = (const float*)d_in[0];   // [64,3,512,512]
  const float* W    = (const float*)d_in[1];   // [64,24]
  const float* bias = (const float*)d_in[2];   // [64]
  float* out = (float*)d_out;                  // [64,64]

  // ws layout: per-column partials | transposed bin table | bf16 F^T
  const size_t partial_bytes = (size_t)64 * W2 * 24 * sizeof(float);  // 1.58 MB
  size_t off_bins = (partial_bytes + 255) & ~(size_t)255;
  const size_t bins_bytes = (size_t)W2 * 512;
  size_t off_F = ((off_bins + bins_bytes) + 255) & ~(size_t)255;

  float* partial = (float*)d_ws;
  unsigned char* binsT = (unsigned char*)d_ws + off_bins;
  unsigned* FT = (unsigned*)((char*)d_ws + off_F);

  const size_t per_batch = (size_t)3 * W2 * FTS * sizeof(unsigned);  // 1.58 MB
  size_t avail = ws_size > off_F ? ws_size - off_F : 0;
  int bpc = (int)(avail / per_batch);
  if (bpc < 1) bpc = 1;
  if (bpc > 64) bpc = 64;

  pass0_kernel<<<W2, TPB0, 0, stream>>>(binsT);

  for (int b0 = 0; b0 < 64; b0 += bpc) {
    int nb = (64 - b0) < bpc ? (64 - b0) : bpc;
    pass1_kernel<<<nb * 3 * 16, TPB1, 0, stream>>>(x, FT, b0 * 3);
    pass2_kernel<<<nb * W2, TPB2, 0, stream>>>(FT, binsT, partial, b0);
  }
  pass3_kernel<<<64, TPB0, 0, stream>>>(partial, W, bias, out);
}

// Round 13
// 182.589 us; speedup vs baseline: 1.1717x; 1.1717x over previous
//
#include <hip/hip_runtime.h>
#include <math.h>

// SpectrumHead: rfft2(512x512) magnitude -> radial/angular histogram -> linear proj.
// B=64, C=3, H=512, W=512, W2=257, K_BINS=16, O_BINS=8, proj=64.
//
// Three-step 512 = 8x8x8 register FFT in WAVE-PRIVATE LDS segments (same-wave
// LDS ops are in-order on CDNA -> no barriers between transpose phases; only
// sched_barrier(0) pins compiler order). Swizzle PH(i) = i ^ 9*(i>>6&7), written
// in folded form (C ^ 9q) + 64q. All FFT phases at the wave64 LDS bank floor.
//
// F intermediate stored TRANSPOSED + bf16-packed: FT[ch_img][j][i] (uint32 per
// complex) -> pass2 column loads are contiguous 2KB runs, no cross-wave staging.
//
// Pass 0: transposed bin table binsT[j][i].
// Pass 1: TPB 1024 (16 waves = 16 row-pairs). Wave-private FFT + Hermitian
//         unpack + bf16 pack; ONE barrier; transposed write-out (128B i-runs).
// Pass 2: TPB 256, wave = one column j (r11 structure — r12's wave-per-channel
//         split regressed: 4x block-fixed-overhead, latency was already TLP-
//         hidden). fp32 LDS segments (no pack/unpack on transposes, -12% VALU);
//         17.4 KB LDS -> occupancy stays wave-capped at 8 blocks/CU.
// Pass 3: reduce 65 tile-partials per batch, normalize, h @ W.T + b.
//
// Twiddles: no LDS tables; per-thread sincosf + chained powers.
//
// LAUNCH BOUNDS CALIBRATION (empirical, this toolchain): reported VGPR cap
// ~= 256/arg2 (r3:3->80, r4/6:6->40, r7:8->32, r8:4->56 no-spill). arg2=4 ->
// cap 64; FFT kernels need ~40-50.

#define TPB0 256
#define TPB1 1024
#define TPB2 256
#define W2 257
#define NTILE 65           // pass2: 4 columns per block
#define CS 529             // per-wave segment stride, float2 units
#define CSU (2*CS)         // same stride in uint units (1058)
#define FTS 512            // FT row stride in uints (2KB rows, line-aligned)
#define PI_F 3.14159265358979323846f
#define TWO_PI_F 6.28318530717958647692f
#define SB() __builtin_amdgcn_sched_barrier(0)
#define PH(i) ((i) ^ ((((i) >> 6) & 7) * 9))

// exp(-2*pi*i*k/32), k = 0..15
static constexpr float TW32_RE[16] = {
   1.0f,          0.98078528f,  0.92387953f,  0.83146961f,
   0.70710678f,   0.55557023f,  0.38268343f,  0.19509032f,
   0.0f,         -0.19509032f, -0.38268343f, -0.55557023f,
  -0.70710678f,  -0.83146961f, -0.92387953f, -0.98078528f };
static constexpr float TW32_IM[16] = {
  -0.0f,         -0.19509032f, -0.38268343f, -0.55557023f,
  -0.70710678f,  -0.83146961f, -0.92387953f, -0.98078528f,
  -1.0f,         -0.98078528f, -0.92387953f, -0.83146961f,
  -0.70710678f,  -0.55557023f, -0.38268343f, -0.19509032f };

static constexpr int BR3[8] = {0,4,2,6,1,5,3,7};

__device__ __forceinline__ float2 cmulf(float2 a, float2 b) {
  return make_float2(a.x*b.x - a.y*b.y, a.x*b.y + a.y*b.x);
}
__device__ __forceinline__ unsigned bfpack(float2 v) {
  unsigned a = __float_as_uint(v.x) >> 16;
  unsigned b = __float_as_uint(v.y) & 0xFFFF0000u;
  return b | a;
}
__device__ __forceinline__ float2 bfunpack(unsigned p) {
  return make_float2(__uint_as_float(p << 16), __uint_as_float(p & 0xFFFF0000u));
}

// In-register DIT FFT8, twiddles from TW32. Input bit-rev permuted; output
// natural. Fully unrolled -> VGPRs.
template <int LOGN>
__device__ __forceinline__ void fft_reg(float2* z) {
  const int N = 1 << LOGN;
  #pragma unroll
  for (int s = 0; s < LOGN; ++s) {
    const int h = 1 << s;
    #pragma unroll
    for (int g0 = 0; g0 < N; g0 += 2 * h) {
      #pragma unroll
      for (int jj = 0; jj < h; ++jj) {
        const int k = jj << (4 - s);
        const float wr = TW32_RE[k], wi = TW32_IM[k];
        float2 a = z[g0 + jj];
        float2 b = z[g0 + jj + h];
        float tr = b.x * wr - b.y * wi;
        float ti = b.x * wi + b.y * wr;
        z[g0 + jj]     = make_float2(a.x + tr, a.y + ti);
        z[g0 + jj + h] = make_float2(a.x - tr, a.y - ti);
      }
    }
  }
}

// Apply chained twiddle powers: z[k] *= base^k, k = 1..7.
__device__ __forceinline__ void twiddle_chain(float2* z, float2 base) {
  float2 wk = base;
  #pragma unroll
  for (int k = 1; k < 8; ++k) {
    z[k] = cmulf(z[k], wk);
    if (k < 7) wk = cmulf(wk, base);
  }
}

__device__ __forceinline__ void get_bins(int i, int j, int& rb, int& ob) {
  float yy = -1.0f + (float)i * (2.0f / 511.0f);
  float xx = (float)j * (1.0f / 256.0f);
  float rr = sqrtf(yy * yy + xx * xx);
  rr = fminf(rr, 1.0f - 1e-8f);
  float th = atan2f(yy, xx + 1e-9f) + 1.57079632679489662f;
  rb = (int)(rr * 16.0f);
  rb = rb < 0 ? 0 : (rb > 15 ? 15 : rb);
  ob = (int)((th / PI_F) * 8.0f);
  ob = ob < 0 ? 0 : (ob > 7 ? 7 : ob);
}

// Pass 0: TRANSPOSED bin table binsT[j][i] = rb | ob<<4. blockIdx.x = j.
__global__ __launch_bounds__(TPB0) void pass0_kernel(unsigned char* __restrict__ binsT) {
  int j = blockIdx.x;           // 0..256
  #pragma unroll
  for (int e = 0; e < 2; e++) {
    int i = threadIdx.x + e * 256;
    int rb, ob;
    get_bins(i, j, rb, ob);
    binsT[(size_t)j * 512 + i] = (unsigned char)(rb | (ob << 4));
  }
}

// Pass 1: blockIdx.x = ic_local*16 + segblk. Wave wv = row-pair
// rp = segblk*16 + wv (rows 2rp, 2rp+1 packed as one complex 512-pt FFT).
// Output: FT[ic_local][j][i] bf16-packed, i-chunk [segblk*32, +32).
__global__ __launch_bounds__(TPB1, 4) void pass1_kernel(
    const float* __restrict__ x, unsigned* __restrict__ FT, int ic0) {
  __shared__ float2 xbuf[16 * CS];       // 67.7 KB: 16 wave-private segments
  int t = threadIdx.x;
  int segblk = blockIdx.x & 15;
  int ic_local = blockIdx.x >> 4;
  int wv = t >> 6;
  int u = t & 63;
  int rp = segblk * 16 + wv;
  const float* row0 = x + (((size_t)(ic0 + ic_local)) * 512 + (size_t)rp * 2) * 512;
  const float* row1 = row0 + 512;
  float2* seg = xbuf + wv * CS;
  unsigned* useg = (unsigned*)xbuf + wv * CSU;

  const int ul = u & 7, wq = u >> 3;
  const int x9 = 9 * wq, b64 = 64 * wq;

  float2 w1, w64;
  { float sn, cs;
    sincosf(-TWO_PI_F * (float)u * (1.0f / 512.0f), &sn, &cs);  w1  = make_float2(cs, sn);
    sincosf(-TWO_PI_F * (float)ul * (1.0f / 64.0f), &sn, &cs);  w64 = make_float2(cs, sn); }

  // step 1: FFT8 over m, twiddle W512^(u*k3) via chain
  float2 z[8];
  #pragma unroll
  for (int m = 0; m < 8; ++m)
    z[BR3[m]] = make_float2(row0[u + 64 * m], row1[u + 64 * m]);
  fft_reg<3>(z);
  twiddle_chain(z, w1);
  SB();
  #pragma unroll
  for (int k3 = 0; k3 < 8; ++k3) seg[(u ^ (9 * k3)) + 64 * k3] = z[k3];   // L1[k3][u]
  SB();
  // step 2: FFT8 over g2, twiddle W64^(ul*K2) via chain
  #pragma unroll
  for (int g2 = 0; g2 < 8; ++g2) z[BR3[g2]] = seg[((ul + 8 * g2) ^ x9) + b64];
  fft_reg<3>(z);
  twiddle_chain(z, w64);
  SB();
  #pragma unroll
  for (int K2 = 0; K2 < 8; ++K2) seg[((K2 * 8 + ul) ^ x9) + b64] = z[K2]; // L2
  SB();
  // step 3: FFT8 over g1 -> Z[wq + 8ul + 64K1]
  #pragma unroll
  for (int gg = 0; gg < 8; ++gg) z[BR3[gg]] = seg[((ul * 8 + gg) ^ x9) + b64];
  fft_reg<3>(z);
  SB();
  #pragma unroll
  for (int K1 = 0; K1 < 8; ++K1)
    seg[((wq + 8 * ul) ^ (9 * K1)) + 64 * K1] = z[K1];                    // Z natural, swizzled
  SB();
  // Hermitian unpack (fp32) + bf16 pack; stash as uints in own segment.
  unsigned p0[4], p1[4];
  #pragma unroll
  for (int e = 0; e < 4; ++e) {
    int k = u + 64 * e;
    int km = (512 - k) & 511;
    float2 zk = seg[PH(k)];
    float2 zm = seg[PH(km)];
    p0[e] = bfpack(make_float2(0.5f * (zk.x + zm.x),  0.5f * (zk.y - zm.y)));
    p1[e] = bfpack(make_float2(0.5f * (zk.y + zm.y), -0.5f * (zk.x - zm.x)));
  }
  unsigned p0n = 0, p1n = 0;
  if (u == 0) {
    float2 zk = seg[PH(256)];            // Nyquist (self-paired)
    p0n = bfpack(make_float2(zk.x, 0.0f));
    p1n = bfpack(make_float2(zk.y, 0.0f));
  }
  SB();
  #pragma unroll
  for (int e = 0; e < 4; ++e) {
    int k = u + 64 * e;
    useg[k] = p0[e];                     // row 2rp   spectrum at [k]
    useg[257 + k] = p1[e];               // row 2rp+1 spectrum at [257+k]
  }
  if (u == 0) { useg[256] = p0n; useg[513] = p1n; }
  __syncthreads();

  // transposed write-out: for each j, 32 consecutive i (128B run).
  unsigned* FTc = FT + (size_t)ic_local * (W2 * FTS);
  int i0 = segblk * 32;
  const unsigned* xb = (const unsigned*)xbuf;
  #pragma unroll
  for (int it = 0; it < 9; ++it) {
    int idx = t + TPB1 * it;
    if (idx < W2 * 32) {
      int j = idx >> 5;
      int il = idx & 31;                 // i_local = 2*pair + hi
      unsigned v = xb[(il >> 1) * CSU + (il & 1) * 257 + j];
      FTc[(size_t)j * FTS + i0 + il] = v;
    }
  }
}

// Pass 2: blockIdx.x = b_local*NTILE + tile. Wave wv owns column j = tile*4+wv.
// Contiguous 2KB column loads; wave-private fp32 FFT (bf16 only at the global
// boundary); zero staging barriers.
__global__ __launch_bounds__(TPB2, 4) void pass2_kernel(
    const unsigned* __restrict__ FT, const unsigned char* __restrict__ binsT,
    float* __restrict__ partial, int b0) {
  __shared__ float2 xbuf[4 * CS];        // 16.9 KB: 4 wave-private fp32 segments
  __shared__ float hist[128];            // combined bins: rb + 16*ob
  int t = threadIdx.x;
  int tile = blockIdx.x % NTILE;
  int b_local = blockIdx.x / NTILE;
  int wv = t >> 6;
  int u = t & 63;
  int j = tile * 4 + wv;
  bool jvalid = (j < W2);
  float2* seg = xbuf + wv * CS;
  const int ul = u & 7, wq = u >> 3;
  const int x9 = 9 * wq, b64 = 64 * wq;

  if (t < 128) hist[t] = 0.0f;
  __syncthreads();

  if (jvalid) {
    float2 w1, w64;
    { float sn, cs;
      sincosf(-TWO_PI_F * (float)u * (1.0f / 512.0f), &sn, &cs);  w1  = make_float2(cs, sn);
      sincosf(-TWO_PI_F * (float)ul * (1.0f / 64.0f), &sn, &cs);  w64 = make_float2(cs, sn); }

    float mag[8];
    #pragma unroll
    for (int q = 0; q < 8; ++q) mag[q] = 0.0f;

    for (int c = 0; c < 3; ++c) {
      const unsigned* col = FT + ((size_t)(b_local * 3 + c) * W2 + j) * FTS;
      float2 z[8];
      #pragma unroll
      for (int m = 0; m < 8; ++m) z[BR3[m]] = bfunpack(col[u + 64 * m]);
      fft_reg<3>(z);
      twiddle_chain(z, w1);
      SB();
      #pragma unroll
      for (int k3 = 0; k3 < 8; ++k3) seg[(u ^ (9 * k3)) + 64 * k3] = z[k3];
      SB();
      #pragma unroll
      for (int g2 = 0; g2 < 8; ++g2) z[BR3[g2]] = seg[((ul + 8 * g2) ^ x9) + b64];
      fft_reg<3>(z);
      twiddle_chain(z, w64);
      SB();
      #pragma unroll
      for (int K2 = 0; K2 < 8; ++K2) seg[((K2 * 8 + ul) ^ x9) + b64] = z[K2];
      SB();
      #pragma unroll
      for (int gg = 0; gg < 8; ++gg) z[BR3[gg]] = seg[((ul * 8 + gg) ^ x9) + b64];
      fft_reg<3>(z);
      #pragma unroll
      for (int K1 = 0; K1 < 8; ++K1)
        mag[K1] += sqrtf(z[K1].x * z[K1].x + z[K1].y * z[K1].y);
      SB();                              // seg reads done before next channel's writes
    }

    const unsigned char* bj = binsT + (size_t)j * 512;
    #pragma unroll
    for (int K1 = 0; K1 < 8; ++K1) {
      int row = wq + 8 * ul + 64 * K1;
      int code = bj[row];                // coalesced 64B run per K1
      // scale: ortho (1/512) * channel mean (1/3) = 1/1536
      atomicAdd(&hist[code], log1pf(mag[K1] * (1.0f / 1536.0f)));
    }
  }
  __syncthreads();

  // fold 128 combined bins -> 16 radial + 8 angular partials
  int b = b0 + b_local;
  if (t < 16) {
    float s = 0.0f;
    #pragma unroll
    for (int ob = 0; ob < 8; ++ob) s += hist[t + 16 * ob];
    partial[((size_t)b * NTILE + tile) * 24 + t] = s;
  } else if (t < 24) {
    float s = 0.0f;
    int ob = t - 16;
    #pragma unroll
    for (int rb = 0; rb < 16; ++rb) s += hist[rb + 16 * ob];
    partial[((size_t)b * NTILE + tile) * 24 + t] = s;
  }
}

// Pass 3: one block per batch. Reduce NTILE partials, normalize, project.
__global__ __launch_bounds__(TPB0) void pass3_kernel(
    const float* __restrict__ partial, const float* __restrict__ W,
    const float* __restrict__ bias, float* __restrict__ out) {
  __shared__ float h[24];
  __shared__ float hn[24];
  int b = blockIdx.x;
  int t = threadIdx.x;
  if (t < 24) {
    float s = 0.0f;
    for (int tile = 0; tile < NTILE; tile++)
      s += partial[((size_t)b * NTILE + tile) * 24 + t];
    h[t] = s;
  }
  __syncthreads();
  if (t == 0) {
    float rs = 0.0f, as = 0.0f;
    for (int k = 0; k < 16; k++) rs += h[k];
    for (int k = 16; k < 24; k++) as += h[k];
    for (int k = 0; k < 16; k++) hn[k] = h[k] / (rs + 1e-6f);
    for (int k = 16; k < 24; k++) hn[k] = h[k] / (as + 1e-6f);
  }
  __syncthreads();
  if (t < 64) {
    float acc = bias[t];
    #pragma unroll
    for (int k = 0; k < 24; k++) acc += hn[k] * W[t * 24 + k];
    out[b * 64 + t] = acc;
  }
}

extern "C" void kernel_launch(void* const* d_in, const int* in_sizes, int n_in,
                              void* d_out, int out_size, void* d_ws, size_t ws_size,
                              hipStream_t stream) {
  const float* x    = (const float*)d_in[0];   // [64,3,512,512]
  const float* W    = (const float*)d_in[1];   // [64,24]
  const float* bias = (const float*)d_in[2];   // [64]
  float* out = (float*)d_out;                  // [64,64]

  // ws layout: tile partials | transposed bin table | bf16 F^T
  const size_t partial_bytes = (size_t)64 * NTILE * 24 * sizeof(float);
  size_t off_bins = (partial_bytes + 255) & ~(size_t)255;
  const size_t bins_bytes = (size_t)W2 * 512;
  size_t off_F = ((off_bins + bins_bytes) + 255) & ~(size_t)255;

  float* partial = (float*)d_ws;
  unsigned char* binsT = (unsigned char*)d_ws + off_bins;
  unsigned* FT = (unsigned*)((char*)d_ws + off_F);

  const size_t per_batch = (size_t)3 * W2 * FTS * sizeof(unsigned);  // 1.58 MB
  size_t avail = ws_size > off_F ? ws_size - off_F : 0;
  int bpc = (int)(avail / per_batch);
  if (bpc < 1) bpc = 1;
  if (bpc > 64) bpc = 64;

  pass0_kernel<<<W2, TPB0, 0, stream>>>(binsT);

  for (int b0 = 0; b0 < 64; b0 += bpc) {
    int nb = (64 - b0) < bpc ? (64 - b0) : bpc;
    pass1_kernel<<<nb * 3 * 16, TPB1, 0, stream>>>(x, FT, b0 * 3);
    pass2_kernel<<<nb * NTILE, TPB2, 0, stream>>>(FT, binsT, partial, b0);
  }
  pass3_kernel<<<64, TPB0, 0, stream>>>(partial, W, bias, out);
}

// Round 14
// 181.297 us; speedup vs baseline: 1.1801x; 1.0071x over previous
//
#include <hip/hip_runtime.h>
#include <math.h>

// SpectrumHead: rfft2(512x512) magnitude -> radial/angular histogram -> linear proj.
// B=64, C=3, H=512, W=512, W2=257, K_BINS=16, O_BINS=8, proj=64.
//
// Three-step 512 = 8x8x8 register FFT in WAVE-PRIVATE LDS segments (same-wave
// LDS ops are in-order on CDNA -> no barriers between transpose phases; only
// sched_barrier(0) pins compiler order). Swizzle PH(i) = i ^ 9*(i>>6&7), written
// in folded form (C ^ 9q) + 64q. All FFT phases at the wave64 LDS bank floor.
//
// F intermediate stored TRANSPOSED + bf16-packed: FT[ch_img][j][i] (uint32 per
// complex) -> pass2 column loads are contiguous 2KB runs, no cross-wave staging.
//
// Pass 0: transposed bin table binsT[j][i].
// Pass 1: TPB 1024 (16 waves = 16 row-pairs). Wave-private FFT + Hermitian
//         unpack + bf16 pack; ONE barrier; transposed write-out (128B i-runs).
// Pass 2: TPB 256, wave = TWO columns (jA, jB = jA+4) with fully interleaved
//         FFT chains in separate registers + separate bf16 LDS segments.
//         ILP covers the serial LDS dependency (TLP is VGPR-cap-blocked:
//         arg2>=5 would cap <=51 regs < ~55 needed). bf16 LDS = b32 traffic
//         (r13 showed fp32/b64 LDS is a net wash-to-loss). 8 cols/block ->
//         2112 blocks, halved per-block fixed overhead (r12 lesson).
// Pass 3: reduce 33 tile-partials per batch, normalize, h @ W.T + b.
//
// Twiddles: no LDS tables; per-thread sincosf + chained powers.
//
// LAUNCH BOUNDS CALIBRATION (empirical, this toolchain): reported VGPR cap
// ~= 256/arg2 (r3:3->80, r4/6:6->40, r7:8->32, r8:4->56 no-spill). arg2=4 ->
// cap 64; pass2 ILP needs ~62 (watch WRITE_SIZE for spill; fallback = r11).

#define TPB0 256
#define TPB1 1024
#define TPB2 256
#define W2 257
#define NTILE 33           // pass2: 8 columns per block (2 per wave)
#define CS 529             // pass1 per-wave segment stride, float2 units
#define CSU (2*CS)         // same stride in uint units (1058)
#define CSB 513            // pass2 per-col segment stride, uint units (==1 mod 32)
#define FTS 512            // FT row stride in uints (2KB rows, line-aligned)
#define PI_F 3.14159265358979323846f
#define TWO_PI_F 6.28318530717958647692f
#define SB() __builtin_amdgcn_sched_barrier(0)
#define PH(i) ((i) ^ ((((i) >> 6) & 7) * 9))

// exp(-2*pi*i*k/32), k = 0..15
static constexpr float TW32_RE[16] = {
   1.0f,          0.98078528f,  0.92387953f,  0.83146961f,
   0.70710678f,   0.55557023f,  0.38268343f,  0.19509032f,
   0.0f,         -0.19509032f, -0.38268343f, -0.55557023f,
  -0.70710678f,  -0.83146961f, -0.92387953f, -0.98078528f };
static constexpr float TW32_IM[16] = {
  -0.0f,         -0.19509032f, -0.38268343f, -0.55557023f,
  -0.70710678f,  -0.83146961f, -0.92387953f, -0.98078528f,
  -1.0f,         -0.98078528f, -0.92387953f, -0.83146961f,
  -0.70710678f,  -0.55557023f, -0.38268343f, -0.19509032f };

static constexpr int BR3[8] = {0,4,2,6,1,5,3,7};

__device__ __forceinline__ float2 cmulf(float2 a, float2 b) {
  return make_float2(a.x*b.x - a.y*b.y, a.x*b.y + a.y*b.x);
}
__device__ __forceinline__ unsigned bfpack(float2 v) {
  unsigned a = __float_as_uint(v.x) >> 16;
  unsigned b = __float_as_uint(v.y) & 0xFFFF0000u;
  return b | a;
}
__device__ __forceinline__ float2 bfunpack(unsigned p) {
  return make_float2(__uint_as_float(p << 16), __uint_as_float(p & 0xFFFF0000u));
}

// In-register DIT FFT8, twiddles from TW32. Input bit-rev permuted; output
// natural. Fully unrolled -> VGPRs.
template <int LOGN>
__device__ __forceinline__ void fft_reg(float2* z) {
  const int N = 1 << LOGN;
  #pragma unroll
  for (int s = 0; s < LOGN; ++s) {
    const int h = 1 << s;
    #pragma unroll
    for (int g0 = 0; g0 < N; g0 += 2 * h) {
      #pragma unroll
      for (int jj = 0; jj < h; ++jj) {
        const int k = jj << (4 - s);
        const float wr = TW32_RE[k], wi = TW32_IM[k];
        float2 a = z[g0 + jj];
        float2 b = z[g0 + jj + h];
        float tr = b.x * wr - b.y * wi;
        float ti = b.x * wi + b.y * wr;
        z[g0 + jj]     = make_float2(a.x + tr, a.y + ti);
        z[g0 + jj + h] = make_float2(a.x - tr, a.y - ti);
      }
    }
  }
}

// Apply chained twiddle powers: z[k] *= base^k, k = 1..7.
__device__ __forceinline__ void twiddle_chain(float2* z, float2 base) {
  float2 wk = base;
  #pragma unroll
  for (int k = 1; k < 8; ++k) {
    z[k] = cmulf(z[k], wk);
    if (k < 7) wk = cmulf(wk, base);
  }
}

__device__ __forceinline__ void get_bins(int i, int j, int& rb, int& ob) {
  float yy = -1.0f + (float)i * (2.0f / 511.0f);
  float xx = (float)j * (1.0f / 256.0f);
  float rr = sqrtf(yy * yy + xx * xx);
  rr = fminf(rr, 1.0f - 1e-8f);
  float th = atan2f(yy, xx + 1e-9f) + 1.57079632679489662f;
  rb = (int)(rr * 16.0f);
  rb = rb < 0 ? 0 : (rb > 15 ? 15 : rb);
  ob = (int)((th / PI_F) * 8.0f);
  ob = ob < 0 ? 0 : (ob > 7 ? 7 : ob);
}

// Pass 0: TRANSPOSED bin table binsT[j][i] = rb | ob<<4. blockIdx.x = j.
__global__ __launch_bounds__(TPB0) void pass0_kernel(unsigned char* __restrict__ binsT) {
  int j = blockIdx.x;           // 0..256
  #pragma unroll
  for (int e = 0; e < 2; e++) {
    int i = threadIdx.x + e * 256;
    int rb, ob;
    get_bins(i, j, rb, ob);
    binsT[(size_t)j * 512 + i] = (unsigned char)(rb | (ob << 4));
  }
}

// Pass 1: blockIdx.x = ic_local*16 + segblk. Wave wv = row-pair
// rp = segblk*16 + wv (rows 2rp, 2rp+1 packed as one complex 512-pt FFT).
// Output: FT[ic_local][j][i] bf16-packed, i-chunk [segblk*32, +32).
__global__ __launch_bounds__(TPB1, 4) void pass1_kernel(
    const float* __restrict__ x, unsigned* __restrict__ FT, int ic0) {
  __shared__ float2 xbuf[16 * CS];       // 67.7 KB: 16 wave-private segments
  int t = threadIdx.x;
  int segblk = blockIdx.x & 15;
  int ic_local = blockIdx.x >> 4;
  int wv = t >> 6;
  int u = t & 63;
  int rp = segblk * 16 + wv;
  const float* row0 = x + (((size_t)(ic0 + ic_local)) * 512 + (size_t)rp * 2) * 512;
  const float* row1 = row0 + 512;
  float2* seg = xbuf + wv * CS;
  unsigned* useg = (unsigned*)xbuf + wv * CSU;

  const int ul = u & 7, wq = u >> 3;
  const int x9 = 9 * wq, b64 = 64 * wq;

  float2 w1, w64;
  { float sn, cs;
    sincosf(-TWO_PI_F * (float)u * (1.0f / 512.0f), &sn, &cs);  w1  = make_float2(cs, sn);
    sincosf(-TWO_PI_F * (float)ul * (1.0f / 64.0f), &sn, &cs);  w64 = make_float2(cs, sn); }

  // step 1: FFT8 over m, twiddle W512^(u*k3) via chain
  float2 z[8];
  #pragma unroll
  for (int m = 0; m < 8; ++m)
    z[BR3[m]] = make_float2(row0[u + 64 * m], row1[u + 64 * m]);
  fft_reg<3>(z);
  twiddle_chain(z, w1);
  SB();
  #pragma unroll
  for (int k3 = 0; k3 < 8; ++k3) seg[(u ^ (9 * k3)) + 64 * k3] = z[k3];   // L1[k3][u]
  SB();
  // step 2: FFT8 over g2, twiddle W64^(ul*K2) via chain
  #pragma unroll
  for (int g2 = 0; g2 < 8; ++g2) z[BR3[g2]] = seg[((ul + 8 * g2) ^ x9) + b64];
  fft_reg<3>(z);
  twiddle_chain(z, w64);
  SB();
  #pragma unroll
  for (int K2 = 0; K2 < 8; ++K2) seg[((K2 * 8 + ul) ^ x9) + b64] = z[K2]; // L2
  SB();
  // step 3: FFT8 over g1 -> Z[wq + 8ul + 64K1]
  #pragma unroll
  for (int gg = 0; gg < 8; ++gg) z[BR3[gg]] = seg[((ul * 8 + gg) ^ x9) + b64];
  fft_reg<3>(z);
  SB();
  #pragma unroll
  for (int K1 = 0; K1 < 8; ++K1)
    seg[((wq + 8 * ul) ^ (9 * K1)) + 64 * K1] = z[K1];                    // Z natural, swizzled
  SB();
  // Hermitian unpack (fp32) + bf16 pack; stash as uints in own segment.
  unsigned p0[4], p1[4];
  #pragma unroll
  for (int e = 0; e < 4; ++e) {
    int k = u + 64 * e;
    int km = (512 - k) & 511;
    float2 zk = seg[PH(k)];
    float2 zm = seg[PH(km)];
    p0[e] = bfpack(make_float2(0.5f * (zk.x + zm.x),  0.5f * (zk.y - zm.y)));
    p1[e] = bfpack(make_float2(0.5f * (zk.y + zm.y), -0.5f * (zk.x - zm.x)));
  }
  unsigned p0n = 0, p1n = 0;
  if (u == 0) {
    float2 zk = seg[PH(256)];            // Nyquist (self-paired)
    p0n = bfpack(make_float2(zk.x, 0.0f));
    p1n = bfpack(make_float2(zk.y, 0.0f));
  }
  SB();
  #pragma unroll
  for (int e = 0; e < 4; ++e) {
    int k = u + 64 * e;
    useg[k] = p0[e];                     // row 2rp   spectrum at [k]
    useg[257 + k] = p1[e];               // row 2rp+1 spectrum at [257+k]
  }
  if (u == 0) { useg[256] = p0n; useg[513] = p1n; }
  __syncthreads();

  // transposed write-out: for each j, 32 consecutive i (128B run).
  unsigned* FTc = FT + (size_t)ic_local * (W2 * FTS);
  int i0 = segblk * 32;
  const unsigned* xb = (const unsigned*)xbuf;
  #pragma unroll
  for (int it = 0; it < 9; ++it) {
    int idx = t + TPB1 * it;
    if (idx < W2 * 32) {
      int j = idx >> 5;
      int il = idx & 31;                 // i_local = 2*pair + hi
      unsigned v = xb[(il >> 1) * CSU + (il & 1) * 257 + j];
      FTc[(size_t)j * FTS + i0 + il] = v;
    }
  }
}

// Pass 2: blockIdx.x = b_local*NTILE + tile. Wave wv owns columns
// jA = tile*8 + wv and jB = jA + 4, processed as two fully interleaved FFT
// chains (independent registers + independent bf16 LDS segments) so each
// column's LDS latency is hidden by the other's VALU work.
__global__ __launch_bounds__(TPB2, 4) void pass2_kernel(
    const unsigned* __restrict__ FT, const unsigned char* __restrict__ binsT,
    float* __restrict__ partial, int b0) {
  __shared__ unsigned xbuf[8 * CSB];     // 16.4 KB: 8 bf16 segments (2/wave)
  __shared__ float hist[128];            // combined bins: rb + 16*ob
  int t = threadIdx.x;
  int tile = blockIdx.x % NTILE;
  int b_local = blockIdx.x / NTILE;
  int wv = t >> 6;
  int u = t & 63;
  int jA = tile * 8 + wv;
  int jB = jA + 4;
  bool validA = (jA < W2), validB = (jB < W2);
  int jAc = validA ? jA : (W2 - 1);      // clamped (valid memory, hist-skipped)
  int jBc = validB ? jB : (W2 - 1);
  unsigned* segA = xbuf + wv * CSB;
  unsigned* segB = xbuf + (wv + 4) * CSB;
  const int ul = u & 7, wq = u >> 3;
  const int x9 = 9 * wq, b64 = 64 * wq;

  if (t < 128) hist[t] = 0.0f;
  __syncthreads();

  float2 w1, w64;
  { float sn, cs;
    sincosf(-TWO_PI_F * (float)u * (1.0f / 512.0f), &sn, &cs);  w1  = make_float2(cs, sn);
    sincosf(-TWO_PI_F * (float)ul * (1.0f / 64.0f), &sn, &cs);  w64 = make_float2(cs, sn); }

  float magA[8], magB[8];
  #pragma unroll
  for (int q = 0; q < 8; ++q) { magA[q] = 0.0f; magB[q] = 0.0f; }

  for (int c = 0; c < 3; ++c) {
    const unsigned* base = FT + (size_t)(b_local * 3 + c) * W2 * FTS;
    const unsigned* colA = base + (size_t)jAc * FTS;
    const unsigned* colB = base + (size_t)jBc * FTS;
    float2 zA[8], zB[8];
    #pragma unroll
    for (int m = 0; m < 8; ++m) zA[BR3[m]] = bfunpack(colA[u + 64 * m]);
    #pragma unroll
    for (int m = 0; m < 8; ++m) zB[BR3[m]] = bfunpack(colB[u + 64 * m]);
    fft_reg<3>(zA);
    fft_reg<3>(zB);
    twiddle_chain(zA, w1);
    twiddle_chain(zB, w1);
    SB();
    #pragma unroll
    for (int k3 = 0; k3 < 8; ++k3) segA[(u ^ (9 * k3)) + 64 * k3] = bfpack(zA[k3]);
    #pragma unroll
    for (int k3 = 0; k3 < 8; ++k3) segB[(u ^ (9 * k3)) + 64 * k3] = bfpack(zB[k3]);
    SB();
    #pragma unroll
    for (int g2 = 0; g2 < 8; ++g2) zA[BR3[g2]] = bfunpack(segA[((ul + 8 * g2) ^ x9) + b64]);
    #pragma unroll
    for (int g2 = 0; g2 < 8; ++g2) zB[BR3[g2]] = bfunpack(segB[((ul + 8 * g2) ^ x9) + b64]);
    fft_reg<3>(zA);
    fft_reg<3>(zB);
    twiddle_chain(zA, w64);
    twiddle_chain(zB, w64);
    SB();
    #pragma unroll
    for (int K2 = 0; K2 < 8; ++K2) segA[((K2 * 8 + ul) ^ x9) + b64] = bfpack(zA[K2]);
    #pragma unroll
    for (int K2 = 0; K2 < 8; ++K2) segB[((K2 * 8 + ul) ^ x9) + b64] = bfpack(zB[K2]);
    SB();
    #pragma unroll
    for (int gg = 0; gg < 8; ++gg) zA[BR3[gg]] = bfunpack(segA[((ul * 8 + gg) ^ x9) + b64]);
    #pragma unroll
    for (int gg = 0; gg < 8; ++gg) zB[BR3[gg]] = bfunpack(segB[((ul * 8 + gg) ^ x9) + b64]);
    fft_reg<3>(zA);
    fft_reg<3>(zB);
    #pragma unroll
    for (int K1 = 0; K1 < 8; ++K1) {
      magA[K1] += sqrtf(zA[K1].x * zA[K1].x + zA[K1].y * zA[K1].y);
      magB[K1] += sqrtf(zB[K1].x * zB[K1].x + zB[K1].y * zB[K1].y);
    }
    SB();                                // seg reads done before next channel
  }

  if (validA) {
    const unsigned char* bj = binsT + (size_t)jA * 512;
    #pragma unroll
    for (int K1 = 0; K1 < 8; ++K1) {
      int row = wq + 8 * ul + 64 * K1;
      // scale: ortho (1/512) * channel mean (1/3) = 1/1536
      atomicAdd(&hist[bj[row]], log1pf(magA[K1] * (1.0f / 1536.0f)));
    }
  }
  if (validB) {
    const unsigned char* bj = binsT + (size_t)jB * 512;
    #pragma unroll
    for (int K1 = 0; K1 < 8; ++K1) {
      int row = wq + 8 * ul + 64 * K1;
      atomicAdd(&hist[bj[row]], log1pf(magB[K1] * (1.0f / 1536.0f)));
    }
  }
  __syncthreads();

  // fold 128 combined bins -> 16 radial + 8 angular partials
  int b = b0 + b_local;
  if (t < 16) {
    float s = 0.0f;
    #pragma unroll
    for (int ob = 0; ob < 8; ++ob) s += hist[t + 16 * ob];
    partial[((size_t)b * NTILE + tile) * 24 + t] = s;
  } else if (t < 24) {
    float s = 0.0f;
    int ob = t - 16;
    #pragma unroll
    for (int rb = 0; rb < 16; ++rb) s += hist[rb + 16 * ob];
    partial[((size_t)b * NTILE + tile) * 24 + t] = s;
  }
}

// Pass 3: one block per batch. Reduce NTILE partials, normalize, project.
__global__ __launch_bounds__(TPB0) void pass3_kernel(
    const float* __restrict__ partial, const float* __restrict__ W,
    const float* __restrict__ bias, float* __restrict__ out) {
  __shared__ float h[24];
  __shared__ float hn[24];
  int b = blockIdx.x;
  int t = threadIdx.x;
  if (t < 24) {
    float s = 0.0f;
    for (int tile = 0; tile < NTILE; tile++)
      s += partial[((size_t)b * NTILE + tile) * 24 + t];
    h[t] = s;
  }
  __syncthreads();
  if (t == 0) {
    float rs = 0.0f, as = 0.0f;
    for (int k = 0; k < 16; k++) rs += h[k];
    for (int k = 16; k < 24; k++) as += h[k];
    for (int k = 0; k < 16; k++) hn[k] = h[k] / (rs + 1e-6f);
    for (int k = 16; k < 24; k++) hn[k] = h[k] / (as + 1e-6f);
  }
  __syncthreads();
  if (t < 64) {
    float acc = bias[t];
    #pragma unroll
    for (int k = 0; k < 24; k++) acc += hn[k] * W[t * 24 + k];
    out[b * 64 + t] = acc;
  }
}

extern "C" void kernel_launch(void* const* d_in, const int* in_sizes, int n_in,
                              void* d_out, int out_size, void* d_ws, size_t ws_size,
                              hipStream_t stream) {
  const float* x    = (const float*)d_in[0];   // [64,3,512,512]
  const float* W    = (const float*)d_in[1];   // [64,24]
  const float* bias = (const float*)d_in[2];   // [64]
  float* out = (float*)d_out;                  // [64,64]

  // ws layout: tile partials | transposed bin table | bf16 F^T
  const size_t partial_bytes = (size_t)64 * NTILE * 24 * sizeof(float);
  size_t off_bins = (partial_bytes + 255) & ~(size_t)255;
  const size_t bins_bytes = (size_t)W2 * 512;
  size_t off_F = ((off_bins + bins_bytes) + 255) & ~(size_t)255;

  float* partial = (float*)d_ws;
  unsigned char* binsT = (unsigned char*)d_ws + off_bins;
  unsigned* FT = (unsigned*)((char*)d_ws + off_F);

  const size_t per_batch = (size_t)3 * W2 * FTS * sizeof(unsigned);  // 1.58 MB
  size_t avail = ws_size > off_F ? ws_size - off_F : 0;
  int bpc = (int)(avail / per_batch);
  if (bpc < 1) bpc = 1;
  if (bpc > 64) bpc = 64;

  pass0_kernel<<<W2, TPB0, 0, stream>>>(binsT);

  for (int b0 = 0; b0 < 64; b0 += bpc) {
    int nb = (64 - b0) < bpc ? (64 - b0) : bpc;
    pass1_kernel<<<nb * 3 * 16, TPB1, 0, stream>>>(x, FT, b0 * 3);
    pass2_kernel<<<nb * NTILE, TPB2, 0, stream>>>(FT, binsT, partial, b0);
  }
  pass3_kernel<<<64, TPB0, 0, stream>>>(partial, W, bias, out);
}

// Round 15
// 171.236 us; speedup vs baseline: 1.2494x; 1.0588x over previous
//
#include <hip/hip_runtime.h>
#include <math.h>

// SpectrumHead: rfft2(512x512) magnitude -> radial/angular histogram -> linear proj.
// B=64, C=3, H=512, W=512, W2=257, K_BINS=16, O_BINS=8, proj=64.
//
// Three-step 512 = 8x8x8 register FFT in WAVE-PRIVATE LDS segments (same-wave
// LDS ops are in-order on CDNA -> no barriers between transpose phases; only
// sched_barrier(0) pins compiler order). Swizzle PH(i) = i ^ 9*(i>>6&7), written
// in folded form (C ^ 9q) + 64q. All FFT phases at the wave64 LDS bank floor.
//
// FFT8 core is HAND-SPECIALIZED (r15): stage twiddles {1}, {1,-i},
// {1, c(1-i), -i, -c(1+i)} folded — mul-by--i becomes swizzle+negate inside
// add/sub; only 4 real mults per FFT8 (~56 VALU vs ~120 generic; compiler
// can't fold +-0.0/1.0 mults without fast-math). Bit-identical semantics.
//
// F intermediate stored TRANSPOSED + bf16-packed: FT[ch_img][j][i] (uint32 per
// complex) -> pass2 column loads are contiguous 2KB runs, no cross-wave staging.
//
// Pass 0: transposed bin table binsT[j][i].
// Pass 1: TPB 1024 (16 waves = 16 row-pairs). Wave-private FFT + Hermitian
//         unpack + bf16 pack; ONE barrier; transposed write-out (128B i-runs).
// Pass 2: TPB 256, wave = one column j (r11 structure — r12 ch-split, r13 fp32
//         LDS, r14 2-col ILP all flat-to-worse). bf16 LDS segments.
// Pass 3: reduce 65 tile-partials per batch, normalize, h @ W.T + b.
//
// Twiddles: no LDS tables; per-thread sincosf + chained powers.
//
// LAUNCH BOUNDS CALIBRATION (empirical, this toolchain): reported VGPR cap
// ~= 256/arg2 (r3:3->80, r4/6:6->40, r7:8->32, r8:4->56 no-spill). arg2=4 ->
// cap 64; FFT kernels need ~40-50.

#define TPB0 256
#define TPB1 1024
#define TPB2 256
#define W2 257
#define NTILE 65           // pass2: 4 columns per block
#define CS 529             // pass1 per-wave segment stride, float2 units
#define CSU (2*CS)         // same stride in uint units (1058)
#define CSB 513            // pass2 per-col segment stride, uint units (==1 mod 32)
#define FTS 512            // FT row stride in uints (2KB rows, line-aligned)
#define PI_F 3.14159265358979323846f
#define TWO_PI_F 6.28318530717958647692f
#define SB() __builtin_amdgcn_sched_barrier(0)
#define PH(i) ((i) ^ ((((i) >> 6) & 7) * 9))

static constexpr int BR3[8] = {0,4,2,6,1,5,3,7};

__device__ __forceinline__ float2 cmulf(float2 a, float2 b) {
  return make_float2(a.x*b.x - a.y*b.y, a.x*b.y + a.y*b.x);
}
__device__ __forceinline__ float2 cadd(float2 a, float2 b) {
  return make_float2(a.x + b.x, a.y + b.y);
}
__device__ __forceinline__ float2 csub(float2 a, float2 b) {
  return make_float2(a.x - b.x, a.y - b.y);
}
__device__ __forceinline__ float2 cmulnegi(float2 a) {   // a * (-i)
  return make_float2(a.y, -a.x);
}
__device__ __forceinline__ unsigned bfpack(float2 v) {
  unsigned a = __float_as_uint(v.x) >> 16;
  unsigned b = __float_as_uint(v.y) & 0xFFFF0000u;
  return b | a;
}
__device__ __forceinline__ float2 bfunpack(unsigned p) {
  return make_float2(__uint_as_float(p << 16), __uint_as_float(p & 0xFFFF0000u));
}

// Specialized in-register DIT FFT8. Input bit-rev permuted; output natural.
// Exactly the generic radix-2 loop with stage twiddles constant-folded:
// s0: w=1; s1: w in {1,-i}; s2: w in {1, C(1-i), -i, -C(1+i)}, C = sqrt(2)/2.
__device__ __forceinline__ void fft8(float2* z) {
  const float C = 0.70710678118654752f;
  float2 t;
  // stage 1 (pairs (0,1),(2,3),(4,5),(6,7), w=1)
  t = z[1]; z[1] = csub(z[0], t); z[0] = cadd(z[0], t);
  t = z[3]; z[3] = csub(z[2], t); z[2] = cadd(z[2], t);
  t = z[5]; z[5] = csub(z[4], t); z[4] = cadd(z[4], t);
  t = z[7]; z[7] = csub(z[6], t); z[6] = cadd(z[6], t);
  // stage 2 (pairs (0,2),(1,3),(4,6),(5,7); jj=1 -> w = -i)
  t = z[2];           z[2] = csub(z[0], t); z[0] = cadd(z[0], t);
  t = cmulnegi(z[3]); z[3] = csub(z[1], t); z[1] = cadd(z[1], t);
  t = z[6];           z[6] = csub(z[4], t); z[4] = cadd(z[4], t);
  t = cmulnegi(z[7]); z[7] = csub(z[5], t); z[5] = cadd(z[5], t);
  // stage 3 (pairs (0,4),(1,5),(2,6),(3,7); w = 1, C(1-i), -i, -C(1+i))
  t = z[4];           z[4] = csub(z[0], t); z[0] = cadd(z[0], t);
  t = make_float2(C * (z[5].x + z[5].y), C * (z[5].y - z[5].x));
                      z[5] = csub(z[1], t); z[1] = cadd(z[1], t);
  t = cmulnegi(z[6]); z[6] = csub(z[2], t); z[2] = cadd(z[2], t);
  t = make_float2(C * (z[7].y - z[7].x), -C * (z[7].x + z[7].y));
                      z[7] = csub(z[3], t); z[3] = cadd(z[3], t);
}

// Apply chained twiddle powers: z[k] *= base^k, k = 1..7.
__device__ __forceinline__ void twiddle_chain(float2* z, float2 base) {
  float2 wk = base;
  #pragma unroll
  for (int k = 1; k < 8; ++k) {
    z[k] = cmulf(z[k], wk);
    if (k < 7) wk = cmulf(wk, base);
  }
}

__device__ __forceinline__ void get_bins(int i, int j, int& rb, int& ob) {
  float yy = -1.0f + (float)i * (2.0f / 511.0f);
  float xx = (float)j * (1.0f / 256.0f);
  float rr = sqrtf(yy * yy + xx * xx);
  rr = fminf(rr, 1.0f - 1e-8f);
  float th = atan2f(yy, xx + 1e-9f) + 1.57079632679489662f;
  rb = (int)(rr * 16.0f);
  rb = rb < 0 ? 0 : (rb > 15 ? 15 : rb);
  ob = (int)((th / PI_F) * 8.0f);
  ob = ob < 0 ? 0 : (ob > 7 ? 7 : ob);
}

// Pass 0: TRANSPOSED bin table binsT[j][i] = rb | ob<<4. blockIdx.x = j.
__global__ __launch_bounds__(TPB0) void pass0_kernel(unsigned char* __restrict__ binsT) {
  int j = blockIdx.x;           // 0..256
  #pragma unroll
  for (int e = 0; e < 2; e++) {
    int i = threadIdx.x + e * 256;
    int rb, ob;
    get_bins(i, j, rb, ob);
    binsT[(size_t)j * 512 + i] = (unsigned char)(rb | (ob << 4));
  }
}

// Pass 1: blockIdx.x = ic_local*16 + segblk. Wave wv = row-pair
// rp = segblk*16 + wv (rows 2rp, 2rp+1 packed as one complex 512-pt FFT).
// Output: FT[ic_local][j][i] bf16-packed, i-chunk [segblk*32, +32).
__global__ __launch_bounds__(TPB1, 4) void pass1_kernel(
    const float* __restrict__ x, unsigned* __restrict__ FT, int ic0) {
  __shared__ float2 xbuf[16 * CS];       // 67.7 KB: 16 wave-private segments
  int t = threadIdx.x;
  int segblk = blockIdx.x & 15;
  int ic_local = blockIdx.x >> 4;
  int wv = t >> 6;
  int u = t & 63;
  int rp = segblk * 16 + wv;
  const float* row0 = x + (((size_t)(ic0 + ic_local)) * 512 + (size_t)rp * 2) * 512;
  const float* row1 = row0 + 512;
  float2* seg = xbuf + wv * CS;
  unsigned* useg = (unsigned*)xbuf + wv * CSU;

  const int ul = u & 7, wq = u >> 3;
  const int x9 = 9 * wq, b64 = 64 * wq;

  float2 w1, w64;
  { float sn, cs;
    sincosf(-TWO_PI_F * (float)u * (1.0f / 512.0f), &sn, &cs);  w1  = make_float2(cs, sn);
    sincosf(-TWO_PI_F * (float)ul * (1.0f / 64.0f), &sn, &cs);  w64 = make_float2(cs, sn); }

  // step 1: FFT8 over m, twiddle W512^(u*k3) via chain
  float2 z[8];
  #pragma unroll
  for (int m = 0; m < 8; ++m)
    z[BR3[m]] = make_float2(row0[u + 64 * m], row1[u + 64 * m]);
  fft8(z);
  twiddle_chain(z, w1);
  SB();
  #pragma unroll
  for (int k3 = 0; k3 < 8; ++k3) seg[(u ^ (9 * k3)) + 64 * k3] = z[k3];   // L1[k3][u]
  SB();
  // step 2: FFT8 over g2, twiddle W64^(ul*K2) via chain
  #pragma unroll
  for (int g2 = 0; g2 < 8; ++g2) z[BR3[g2]] = seg[((ul + 8 * g2) ^ x9) + b64];
  fft8(z);
  twiddle_chain(z, w64);
  SB();
  #pragma unroll
  for (int K2 = 0; K2 < 8; ++K2) seg[((K2 * 8 + ul) ^ x9) + b64] = z[K2]; // L2
  SB();
  // step 3: FFT8 over g1 -> Z[wq + 8ul + 64K1]
  #pragma unroll
  for (int gg = 0; gg < 8; ++gg) z[BR3[gg]] = seg[((ul * 8 + gg) ^ x9) + b64];
  fft8(z);
  SB();
  #pragma unroll
  for (int K1 = 0; K1 < 8; ++K1)
    seg[((wq + 8 * ul) ^ (9 * K1)) + 64 * K1] = z[K1];                    // Z natural, swizzled
  SB();
  // Hermitian unpack (fp32) + bf16 pack; stash as uints in own segment.
  unsigned p0[4], p1[4];
  #pragma unroll
  for (int e = 0; e < 4; ++e) {
    int k = u + 64 * e;
    int km = (512 - k) & 511;
    float2 zk = seg[PH(k)];
    float2 zm = seg[PH(km)];
    p0[e] = bfpack(make_float2(0.5f * (zk.x + zm.x),  0.5f * (zk.y - zm.y)));
    p1[e] = bfpack(make_float2(0.5f * (zk.y + zm.y), -0.5f * (zk.x - zm.x)));
  }
  unsigned p0n = 0, p1n = 0;
  if (u == 0) {
    float2 zk = seg[PH(256)];            // Nyquist (self-paired)
    p0n = bfpack(make_float2(zk.x, 0.0f));
    p1n = bfpack(make_float2(zk.y, 0.0f));
  }
  SB();
  #pragma unroll
  for (int e = 0; e < 4; ++e) {
    int k = u + 64 * e;
    useg[k] = p0[e];                     // row 2rp   spectrum at [k]
    useg[257 + k] = p1[e];               // row 2rp+1 spectrum at [257+k]
  }
  if (u == 0) { useg[256] = p0n; useg[513] = p1n; }
  __syncthreads();

  // transposed write-out: for each j, 32 consecutive i (128B run).
  unsigned* FTc = FT + (size_t)ic_local * (W2 * FTS);
  int i0 = segblk * 32;
  const unsigned* xb = (const unsigned*)xbuf;
  #pragma unroll
  for (int it = 0; it < 9; ++it) {
    int idx = t + TPB1 * it;
    if (idx < W2 * 32) {
      int j = idx >> 5;
      int il = idx & 31;                 // i_local = 2*pair + hi
      unsigned v = xb[(il >> 1) * CSU + (il & 1) * 257 + j];
      FTc[(size_t)j * FTS + i0 + il] = v;
    }
  }
}

// Pass 2: blockIdx.x = b_local*NTILE + tile. Wave wv owns column j = tile*4+wv.
// Contiguous 2KB column loads; wave-private bf16 FFT; zero staging barriers.
__global__ __launch_bounds__(TPB2, 4) void pass2_kernel(
    const unsigned* __restrict__ FT, const unsigned char* __restrict__ binsT,
    float* __restrict__ partial, int b0) {
  __shared__ unsigned xbuf[4 * CSB];     // 8.2 KB: 4 wave-private segments
  __shared__ float hist[128];            // combined bins: rb + 16*ob
  int t = threadIdx.x;
  int tile = blockIdx.x % NTILE;
  int b_local = blockIdx.x / NTILE;
  int wv = t >> 6;
  int u = t & 63;
  int j = tile * 4 + wv;
  bool jvalid = (j < W2);
  unsigned* seg = xbuf + wv * CSB;
  const int ul = u & 7, wq = u >> 3;
  const int x9 = 9 * wq, b64 = 64 * wq;

  if (t < 128) hist[t] = 0.0f;
  __syncthreads();

  if (jvalid) {
    float2 w1, w64;
    { float sn, cs;
      sincosf(-TWO_PI_F * (float)u * (1.0f / 512.0f), &sn, &cs);  w1  = make_float2(cs, sn);
      sincosf(-TWO_PI_F * (float)ul * (1.0f / 64.0f), &sn, &cs);  w64 = make_float2(cs, sn); }

    float mag[8];
    #pragma unroll
    for (int q = 0; q < 8; ++q) mag[q] = 0.0f;

    for (int c = 0; c < 3; ++c) {
      const unsigned* col = FT + ((size_t)(b_local * 3 + c) * W2 + j) * FTS;
      float2 z[8];
      #pragma unroll
      for (int m = 0; m < 8; ++m) z[BR3[m]] = bfunpack(col[u + 64 * m]);
      fft8(z);
      twiddle_chain(z, w1);
      SB();
      #pragma unroll
      for (int k3 = 0; k3 < 8; ++k3) seg[(u ^ (9 * k3)) + 64 * k3] = bfpack(z[k3]);
      SB();
      #pragma unroll
      for (int g2 = 0; g2 < 8; ++g2) z[BR3[g2]] = bfunpack(seg[((ul + 8 * g2) ^ x9) + b64]);
      fft8(z);
      twiddle_chain(z, w64);
      SB();
      #pragma unroll
      for (int K2 = 0; K2 < 8; ++K2) seg[((K2 * 8 + ul) ^ x9) + b64] = bfpack(z[K2]);
      SB();
      #pragma unroll
      for (int gg = 0; gg < 8; ++gg) z[BR3[gg]] = bfunpack(seg[((ul * 8 + gg) ^ x9) + b64]);
      fft8(z);
      #pragma unroll
      for (int K1 = 0; K1 < 8; ++K1)
        mag[K1] += sqrtf(z[K1].x * z[K1].x + z[K1].y * z[K1].y);
      SB();                              // seg reads done before next channel's writes
    }

    const unsigned char* bj = binsT + (size_t)j * 512;
    #pragma unroll
    for (int K1 = 0; K1 < 8; ++K1) {
      int row = wq + 8 * ul + 64 * K1;
      int code = bj[row];                // coalesced 64B run per K1
      // scale: ortho (1/512) * channel mean (1/3) = 1/1536
      atomicAdd(&hist[code], log1pf(mag[K1] * (1.0f / 1536.0f)));
    }
  }
  __syncthreads();

  // fold 128 combined bins -> 16 radial + 8 angular partials
  int b = b0 + b_local;
  if (t < 16) {
    float s = 0.0f;
    #pragma unroll
    for (int ob = 0; ob < 8; ++ob) s += hist[t + 16 * ob];
    partial[((size_t)b * NTILE + tile) * 24 + t] = s;
  } else if (t < 24) {
    float s = 0.0f;
    int ob = t - 16;
    #pragma unroll
    for (int rb = 0; rb < 16; ++rb) s += hist[rb + 16 * ob];
    partial[((size_t)b * NTILE + tile) * 24 + t] = s;
  }
}

// Pass 3: one block per batch. Reduce NTILE partials, normalize, project.
__global__ __launch_bounds__(TPB0) void pass3_kernel(
    const float* __restrict__ partial, const float* __restrict__ W,
    const float* __restrict__ bias, float* __restrict__ out) {
  __shared__ float h[24];
  __shared__ float hn[24];
  int b = blockIdx.x;
  int t = threadIdx.x;
  if (t < 24) {
    float s = 0.0f;
    for (int tile = 0; tile < NTILE; tile++)
      s += partial[((size_t)b * NTILE + tile) * 24 + t];
    h[t] = s;
  }
  __syncthreads();
  if (t == 0) {
    float rs = 0.0f, as = 0.0f;
    for (int k = 0; k < 16; k++) rs += h[k];
    for (int k = 16; k < 24; k++) as += h[k];
    for (int k = 0; k < 16; k++) hn[k] = h[k] / (rs + 1e-6f);
    for (int k = 16; k < 24; k++) hn[k] = h[k] / (as + 1e-6f);
  }
  __syncthreads();
  if (t < 64) {
    float acc = bias[t];
    #pragma unroll
    for (int k = 0; k < 24; k++) acc += hn[k] * W[t * 24 + k];
    out[b * 64 + t] = acc;
  }
}

extern "C" void kernel_launch(void* const* d_in, const int* in_sizes, int n_in,
                              void* d_out, int out_size, void* d_ws, size_t ws_size,
                              hipStream_t stream) {
  const float* x    = (const float*)d_in[0];   // [64,3,512,512]
  const float* W    = (const float*)d_in[1];   // [64,24]
  const float* bias = (const float*)d_in[2];   // [64]
  float* out = (float*)d_out;                  // [64,64]

  // ws layout: tile partials | transposed bin table | bf16 F^T
  const size_t partial_bytes = (size_t)64 * NTILE * 24 * sizeof(float);
  size_t off_bins = (partial_bytes + 255) & ~(size_t)255;
  const size_t bins_bytes = (size_t)W2 * 512;
  size_t off_F = ((off_bins + bins_bytes) + 255) & ~(size_t)255;

  float* partial = (float*)d_ws;
  unsigned char* binsT = (unsigned char*)d_ws + off_bins;
  unsigned* FT = (unsigned*)((char*)d_ws + off_F);

  const size_t per_batch = (size_t)3 * W2 * FTS * sizeof(unsigned);  // 1.58 MB
  size_t avail = ws_size > off_F ? ws_size - off_F : 0;
  int bpc = (int)(avail / per_batch);
  if (bpc < 1) bpc = 1;
  if (bpc > 64) bpc = 64;

  pass0_kernel<<<W2, TPB0, 0, stream>>>(binsT);

  for (int b0 = 0; b0 < 64; b0 += bpc) {
    int nb = (64 - b0) < bpc ? (64 - b0) : bpc;
    pass1_kernel<<<nb * 3 * 16, TPB1, 0, stream>>>(x, FT, b0 * 3);
    pass2_kernel<<<nb * NTILE, TPB2, 0, stream>>>(FT, binsT, partial, b0);
  }
  pass3_kernel<<<64, TPB0, 0, stream>>>(partial, W, bias, out);
}

// Round 16
// 171.232 us; speedup vs baseline: 1.2494x; 1.0000x over previous
//
#include <hip/hip_runtime.h>
#include <math.h>

// SpectrumHead: rfft2(512x512) magnitude -> radial/angular histogram -> linear proj.
// B=64, C=3, H=512, W=512, W2=257, K_BINS=16, O_BINS=8, proj=64.
//
// Three-step 512 = 8x8x8 register FFT in WAVE-PRIVATE LDS segments (same-wave
// LDS ops are in-order on CDNA -> no barriers between transpose phases; only
// sched_barrier(0) pins compiler order). Swizzle PH(i) = i ^ 9*(i>>6&7), written
// in folded form (C ^ 9q) + 64q. All FFT phases at the wave64 LDS bank floor.
//
// FFT8 core hand-specialized (r15): only 4 real mults per FFT8 (~56 VALU).
// r16: pass2 channel loop software-pipelined — channel c+1's 8 global loads
// issue while channel c's FFT chain runs (packed 8-reg prefetch buffer),
// removing ~2x300cyc of exposed L2/L3 latency per thread.
//
// F intermediate stored TRANSPOSED + bf16-packed: FT[ch_img][j][i] (uint32 per
// complex) -> pass2 column loads are contiguous 2KB runs, no cross-wave staging.
//
// Pass 0: transposed bin table binsT[j][i].
// Pass 1: TPB 1024 (16 waves = 16 row-pairs). Wave-private FFT + Hermitian
//         unpack + bf16 pack; ONE barrier; transposed write-out (128B i-runs).
// Pass 2: TPB 256, wave = one column j (r11 structure — r12 ch-split, r13 fp32
//         LDS, r14 2-col ILP all flat-to-worse). bf16 LDS segments.
// Pass 3: reduce 65 tile-partials per batch, normalize, h @ W.T + b.
//
// Twiddles: no LDS tables; per-thread sincosf + chained powers.
//
// LAUNCH BOUNDS CALIBRATION (empirical, this toolchain): reported VGPR cap
// ~= 256/arg2 (r3:3->80, r4/6:6->40, r7:8->32, r8:4->56 no-spill). arg2=4 ->
// cap 64; pass2 peak ~55 with prefetch buffer (watch absmax/total for spill).

#define TPB0 256
#define TPB1 1024
#define TPB2 256
#define W2 257
#define NTILE 65           // pass2: 4 columns per block
#define CS 529             // pass1 per-wave segment stride, float2 units
#define CSU (2*CS)         // same stride in uint units (1058)
#define CSB 513            // pass2 per-col segment stride, uint units (==1 mod 32)
#define FTS 512            // FT row stride in uints (2KB rows, line-aligned)
#define PI_F 3.14159265358979323846f
#define TWO_PI_F 6.28318530717958647692f
#define SB() __builtin_amdgcn_sched_barrier(0)
#define PH(i) ((i) ^ ((((i) >> 6) & 7) * 9))

static constexpr int BR3[8] = {0,4,2,6,1,5,3,7};

__device__ __forceinline__ float2 cmulf(float2 a, float2 b) {
  return make_float2(a.x*b.x - a.y*b.y, a.x*b.y + a.y*b.x);
}
__device__ __forceinline__ float2 cadd(float2 a, float2 b) {
  return make_float2(a.x + b.x, a.y + b.y);
}
__device__ __forceinline__ float2 csub(float2 a, float2 b) {
  return make_float2(a.x - b.x, a.y - b.y);
}
__device__ __forceinline__ float2 cmulnegi(float2 a) {   // a * (-i)
  return make_float2(a.y, -a.x);
}
__device__ __forceinline__ unsigned bfpack(float2 v) {
  unsigned a = __float_as_uint(v.x) >> 16;
  unsigned b = __float_as_uint(v.y) & 0xFFFF0000u;
  return b | a;
}
__device__ __forceinline__ float2 bfunpack(unsigned p) {
  return make_float2(__uint_as_float(p << 16), __uint_as_float(p & 0xFFFF0000u));
}

// Specialized in-register DIT FFT8. Input bit-rev permuted; output natural.
// Generic radix-2 loop with stage twiddles constant-folded:
// s0: w=1; s1: w in {1,-i}; s2: w in {1, C(1-i), -i, -C(1+i)}, C = sqrt(2)/2.
__device__ __forceinline__ void fft8(float2* z) {
  const float C = 0.70710678118654752f;
  float2 t;
  t = z[1]; z[1] = csub(z[0], t); z[0] = cadd(z[0], t);
  t = z[3]; z[3] = csub(z[2], t); z[2] = cadd(z[2], t);
  t = z[5]; z[5] = csub(z[4], t); z[4] = cadd(z[4], t);
  t = z[7]; z[7] = csub(z[6], t); z[6] = cadd(z[6], t);
  t = z[2];           z[2] = csub(z[0], t); z[0] = cadd(z[0], t);
  t = cmulnegi(z[3]); z[3] = csub(z[1], t); z[1] = cadd(z[1], t);
  t = z[6];           z[6] = csub(z[4], t); z[4] = cadd(z[4], t);
  t = cmulnegi(z[7]); z[7] = csub(z[5], t); z[5] = cadd(z[5], t);
  t = z[4];           z[4] = csub(z[0], t); z[0] = cadd(z[0], t);
  t = make_float2(C * (z[5].x + z[5].y), C * (z[5].y - z[5].x));
                      z[5] = csub(z[1], t); z[1] = cadd(z[1], t);
  t = cmulnegi(z[6]); z[6] = csub(z[2], t); z[2] = cadd(z[2], t);
  t = make_float2(C * (z[7].y - z[7].x), -C * (z[7].x + z[7].y));
                      z[7] = csub(z[3], t); z[3] = cadd(z[3], t);
}

// Apply chained twiddle powers: z[k] *= base^k, k = 1..7.
__device__ __forceinline__ void twiddle_chain(float2* z, float2 base) {
  float2 wk = base;
  #pragma unroll
  for (int k = 1; k < 8; ++k) {
    z[k] = cmulf(z[k], wk);
    if (k < 7) wk = cmulf(wk, base);
  }
}

__device__ __forceinline__ void get_bins(int i, int j, int& rb, int& ob) {
  float yy = -1.0f + (float)i * (2.0f / 511.0f);
  float xx = (float)j * (1.0f / 256.0f);
  float rr = sqrtf(yy * yy + xx * xx);
  rr = fminf(rr, 1.0f - 1e-8f);
  float th = atan2f(yy, xx + 1e-9f) + 1.57079632679489662f;
  rb = (int)(rr * 16.0f);
  rb = rb < 0 ? 0 : (rb > 15 ? 15 : rb);
  ob = (int)((th / PI_F) * 8.0f);
  ob = ob < 0 ? 0 : (ob > 7 ? 7 : ob);
}

// Pass 0: TRANSPOSED bin table binsT[j][i] = rb | ob<<4. blockIdx.x = j.
__global__ __launch_bounds__(TPB0) void pass0_kernel(unsigned char* __restrict__ binsT) {
  int j = blockIdx.x;           // 0..256
  #pragma unroll
  for (int e = 0; e < 2; e++) {
    int i = threadIdx.x + e * 256;
    int rb, ob;
    get_bins(i, j, rb, ob);
    binsT[(size_t)j * 512 + i] = (unsigned char)(rb | (ob << 4));
  }
}

// Pass 1: blockIdx.x = ic_local*16 + segblk. Wave wv = row-pair
// rp = segblk*16 + wv (rows 2rp, 2rp+1 packed as one complex 512-pt FFT).
// Output: FT[ic_local][j][i] bf16-packed, i-chunk [segblk*32, +32).
__global__ __launch_bounds__(TPB1, 4) void pass1_kernel(
    const float* __restrict__ x, unsigned* __restrict__ FT, int ic0) {
  __shared__ float2 xbuf[16 * CS];       // 67.7 KB: 16 wave-private segments
  int t = threadIdx.x;
  int segblk = blockIdx.x & 15;
  int ic_local = blockIdx.x >> 4;
  int wv = t >> 6;
  int u = t & 63;
  int rp = segblk * 16 + wv;
  const float* row0 = x + (((size_t)(ic0 + ic_local)) * 512 + (size_t)rp * 2) * 512;
  const float* row1 = row0 + 512;
  float2* seg = xbuf + wv * CS;
  unsigned* useg = (unsigned*)xbuf + wv * CSU;

  const int ul = u & 7, wq = u >> 3;
  const int x9 = 9 * wq, b64 = 64 * wq;

  float2 w1, w64;
  { float sn, cs;
    sincosf(-TWO_PI_F * (float)u * (1.0f / 512.0f), &sn, &cs);  w1  = make_float2(cs, sn);
    sincosf(-TWO_PI_F * (float)ul * (1.0f / 64.0f), &sn, &cs);  w64 = make_float2(cs, sn); }

  // step 1: FFT8 over m, twiddle W512^(u*k3) via chain
  float2 z[8];
  #pragma unroll
  for (int m = 0; m < 8; ++m)
    z[BR3[m]] = make_float2(row0[u + 64 * m], row1[u + 64 * m]);
  fft8(z);
  twiddle_chain(z, w1);
  SB();
  #pragma unroll
  for (int k3 = 0; k3 < 8; ++k3) seg[(u ^ (9 * k3)) + 64 * k3] = z[k3];   // L1[k3][u]
  SB();
  // step 2: FFT8 over g2, twiddle W64^(ul*K2) via chain
  #pragma unroll
  for (int g2 = 0; g2 < 8; ++g2) z[BR3[g2]] = seg[((ul + 8 * g2) ^ x9) + b64];
  fft8(z);
  twiddle_chain(z, w64);
  SB();
  #pragma unroll
  for (int K2 = 0; K2 < 8; ++K2) seg[((K2 * 8 + ul) ^ x9) + b64] = z[K2]; // L2
  SB();
  // step 3: FFT8 over g1 -> Z[wq + 8ul + 64K1]
  #pragma unroll
  for (int gg = 0; gg < 8; ++gg) z[BR3[gg]] = seg[((ul * 8 + gg) ^ x9) + b64];
  fft8(z);
  SB();
  #pragma unroll
  for (int K1 = 0; K1 < 8; ++K1)
    seg[((wq + 8 * ul) ^ (9 * K1)) + 64 * K1] = z[K1];                    // Z natural, swizzled
  SB();
  // Hermitian unpack (fp32) + bf16 pack; stash as uints in own segment.
  unsigned p0[4], p1[4];
  #pragma unroll
  for (int e = 0; e < 4; ++e) {
    int k = u + 64 * e;
    int km = (512 - k) & 511;
    float2 zk = seg[PH(k)];
    float2 zm = seg[PH(km)];
    p0[e] = bfpack(make_float2(0.5f * (zk.x + zm.x),  0.5f * (zk.y - zm.y)));
    p1[e] = bfpack(make_float2(0.5f * (zk.y + zm.y), -0.5f * (zk.x - zm.x)));
  }
  unsigned p0n = 0, p1n = 0;
  if (u == 0) {
    float2 zk = seg[PH(256)];            // Nyquist (self-paired)
    p0n = bfpack(make_float2(zk.x, 0.0f));
    p1n = bfpack(make_float2(zk.y, 0.0f));
  }
  SB();
  #pragma unroll
  for (int e = 0; e < 4; ++e) {
    int k = u + 64 * e;
    useg[k] = p0[e];                     // row 2rp   spectrum at [k]
    useg[257 + k] = p1[e];               // row 2rp+1 spectrum at [257+k]
  }
  if (u == 0) { useg[256] = p0n; useg[513] = p1n; }
  __syncthreads();

  // transposed write-out: for each j, 32 consecutive i (128B run).
  unsigned* FTc = FT + (size_t)ic_local * (W2 * FTS);
  int i0 = segblk * 32;
  const unsigned* xb = (const unsigned*)xbuf;
  #pragma unroll
  for (int it = 0; it < 9; ++it) {
    int idx = t + TPB1 * it;
    if (idx < W2 * 32) {
      int j = idx >> 5;
      int il = idx & 31;                 // i_local = 2*pair + hi
      unsigned v = xb[(il >> 1) * CSU + (il & 1) * 257 + j];
      FTc[(size_t)j * FTS + i0 + il] = v;
    }
  }
}

// Pass 2: blockIdx.x = b_local*NTILE + tile. Wave wv owns column j = tile*4+wv.
// Contiguous 2KB column loads; wave-private bf16 FFT; zero staging barriers.
// Channel loop software-pipelined: channel c+1's loads issue before channel
// c's FFT chain so L2/L3 latency overlaps compute.
__global__ __launch_bounds__(TPB2, 4) void pass2_kernel(
    const unsigned* __restrict__ FT, const unsigned char* __restrict__ binsT,
    float* __restrict__ partial, int b0) {
  __shared__ unsigned xbuf[4 * CSB];     // 8.2 KB: 4 wave-private segments
  __shared__ float hist[128];            // combined bins: rb + 16*ob
  int t = threadIdx.x;
  int tile = blockIdx.x % NTILE;
  int b_local = blockIdx.x / NTILE;
  int wv = t >> 6;
  int u = t & 63;
  int j = tile * 4 + wv;
  bool jvalid = (j < W2);
  unsigned* seg = xbuf + wv * CSB;
  const int ul = u & 7, wq = u >> 3;
  const int x9 = 9 * wq, b64 = 64 * wq;

  if (t < 128) hist[t] = 0.0f;
  __syncthreads();

  if (jvalid) {
    float2 w1, w64;
    { float sn, cs;
      sincosf(-TWO_PI_F * (float)u * (1.0f / 512.0f), &sn, &cs);  w1  = make_float2(cs, sn);
      sincosf(-TWO_PI_F * (float)ul * (1.0f / 64.0f), &sn, &cs);  w64 = make_float2(cs, sn); }

    float mag[8];
    #pragma unroll
    for (int q = 0; q < 8; ++q) mag[q] = 0.0f;

    const unsigned* col0 = FT + ((size_t)(b_local * 3 + 0) * W2 + j) * FTS;
    const unsigned* col1 = col0 + (size_t)W2 * FTS;
    const unsigned* col2 = col1 + (size_t)W2 * FTS;

    // prefetch channel 0
    unsigned pk[8];
    #pragma unroll
    for (int m = 0; m < 8; ++m) pk[m] = col0[u + 64 * m];

    #pragma unroll
    for (int c = 0; c < 3; ++c) {
      // unpack current channel from prefetch regs (bit-rev into z)
      float2 z[8];
      #pragma unroll
      for (int m = 0; m < 8; ++m) z[BR3[m]] = bfunpack(pk[m]);
      // issue next channel's loads NOW — latency hides under the FFT chain
      if (c == 0) {
        #pragma unroll
        for (int m = 0; m < 8; ++m) pk[m] = col1[u + 64 * m];
      } else if (c == 1) {
        #pragma unroll
        for (int m = 0; m < 8; ++m) pk[m] = col2[u + 64 * m];
      }
      fft8(z);
      twiddle_chain(z, w1);
      SB();
      #pragma unroll
      for (int k3 = 0; k3 < 8; ++k3) seg[(u ^ (9 * k3)) + 64 * k3] = bfpack(z[k3]);
      SB();
      #pragma unroll
      for (int g2 = 0; g2 < 8; ++g2) z[BR3[g2]] = bfunpack(seg[((ul + 8 * g2) ^ x9) + b64]);
      fft8(z);
      twiddle_chain(z, w64);
      SB();
      #pragma unroll
      for (int K2 = 0; K2 < 8; ++K2) seg[((K2 * 8 + ul) ^ x9) + b64] = bfpack(z[K2]);
      SB();
      #pragma unroll
      for (int gg = 0; gg < 8; ++gg) z[BR3[gg]] = bfunpack(seg[((ul * 8 + gg) ^ x9) + b64]);
      fft8(z);
      #pragma unroll
      for (int K1 = 0; K1 < 8; ++K1)
        mag[K1] += sqrtf(z[K1].x * z[K1].x + z[K1].y * z[K1].y);
      SB();                              // seg reads done before next channel's writes
    }

    const unsigned char* bj = binsT + (size_t)j * 512;
    #pragma unroll
    for (int K1 = 0; K1 < 8; ++K1) {
      int row = wq + 8 * ul + 64 * K1;
      int code = bj[row];                // coalesced 64B run per K1
      // scale: ortho (1/512) * channel mean (1/3) = 1/1536
      atomicAdd(&hist[code], log1pf(mag[K1] * (1.0f / 1536.0f)));
    }
  }
  __syncthreads();

  // fold 128 combined bins -> 16 radial + 8 angular partials
  int b = b0 + b_local;
  if (t < 16) {
    float s = 0.0f;
    #pragma unroll
    for (int ob = 0; ob < 8; ++ob) s += hist[t + 16 * ob];
    partial[((size_t)b * NTILE + tile) * 24 + t] = s;
  } else if (t < 24) {
    float s = 0.0f;
    int ob = t - 16;
    #pragma unroll
    for (int rb = 0; rb < 16; ++rb) s += hist[rb + 16 * ob];
    partial[((size_t)b * NTILE + tile) * 24 + t] = s;
  }
}

// Pass 3: one block per batch. Reduce NTILE partials, normalize, project.
__global__ __launch_bounds__(TPB0) void pass3_kernel(
    const float* __restrict__ partial, const float* __restrict__ W,
    const float* __restrict__ bias, float* __restrict__ out) {
  __shared__ float h[24];
  __shared__ float hn[24];
  int b = blockIdx.x;
  int t = threadIdx.x;
  if (t < 24) {
    float s = 0.0f;
    for (int tile = 0; tile < NTILE; tile++)
      s += partial[((size_t)b * NTILE + tile) * 24 + t];
    h[t] = s;
  }
  __syncthreads();
  if (t == 0) {
    float rs = 0.0f, as = 0.0f;
    for (int k = 0; k < 16; k++) rs += h[k];
    for (int k = 16; k < 24; k++) as += h[k];
    for (int k = 0; k < 16; k++) hn[k] = h[k] / (rs + 1e-6f);
    for (int k = 16; k < 24; k++) hn[k] = h[k] / (as + 1e-6f);
  }
  __syncthreads();
  if (t < 64) {
    float acc = bias[t];
    #pragma unroll
    for (int k = 0; k < 24; k++) acc += hn[k] * W[t * 24 + k];
    out[b * 64 + t] = acc;
  }
}

extern "C" void kernel_launch(void* const* d_in, const int* in_sizes, int n_in,
                              void* d_out, int out_size, void* d_ws, size_t ws_size,
                              hipStream_t stream) {
  const float* x    = (const float*)d_in[0];   // [64,3,512,512]
  const float* W    = (const float*)d_in[1];   // [64,24]
  const float* bias = (const float*)d_in[2];   // [64]
  float* out = (float*)d_out;                  // [64,64]

  // ws layout: tile partials | transposed bin table | bf16 F^T
  const size_t partial_bytes = (size_t)64 * NTILE * 24 * sizeof(float);
  size_t off_bins = (partial_bytes + 255) & ~(size_t)255;
  const size_t bins_bytes = (size_t)W2 * 512;
  size_t off_F = ((off_bins + bins_bytes) + 255) & ~(size_t)255;

  float* partial = (float*)d_ws;
  unsigned char* binsT = (unsigned char*)d_ws + off_bins;
  unsigned* FT = (unsigned*)((char*)d_ws + off_F);

  const size_t per_batch = (size_t)3 * W2 * FTS * sizeof(unsigned);  // 1.58 MB
  size_t avail = ws_size > off_F ? ws_size - off_F : 0;
  int bpc = (int)(avail / per_batch);
  if (bpc < 1) bpc = 1;
  if (bpc > 64) bpc = 64;

  pass0_kernel<<<W2, TPB0, 0, stream>>>(binsT);

  for (int b0 = 0; b0 < 64; b0 += bpc) {
    int nb = (64 - b0) < bpc ? (64 - b0) : bpc;
    pass1_kernel<<<nb * 3 * 16, TPB1, 0, stream>>>(x, FT, b0 * 3);
    pass2_kernel<<<nb * NTILE, TPB2, 0, stream>>>(FT, binsT, partial, b0);
  }
  pass3_kernel<<<64, TPB0, 0, stream>>>(partial, W, bias, out);
}

// Round 17
// 149.331 us; speedup vs baseline: 1.4327x; 1.1467x over previous
//
#include <hip/hip_runtime.h>
#include <math.h>

// SpectrumHead: rfft2(512x512) magnitude -> radial/angular histogram -> linear proj.
// B=64, C=3, H=512, W=512, W2=257, K_BINS=16, O_BINS=8, proj=64.
//
// Three-step 512 = 8x8x8 register FFT in WAVE-PRIVATE LDS segments (same-wave
// LDS ops are in-order on CDNA -> no barriers between transpose phases; only
// sched_barrier(0) pins compiler order). Swizzle PH(i) = i ^ 9*(i>>6&7), written
// in folded form (C ^ 9q) + 64q. All FFT phases at the wave64 LDS bank floor.
//
// FFT8 core hand-specialized (r15): only 4 real mults per FFT8 (~56 VALU).
// r16: channel-loop prefetch (flat — kept, harmless).
// r17: libm -> hardware transcendentals in the FFT kernels: sincosf -> v_sin/
//      v_cos (args are EXACT revolutions -u/512, -ul/64 — no range reduction
//      needed); log1pf(x) -> v_log_f32(1+x)*ln2; sqrtf -> v_sqrt_f32.
//      ~400 of ~1450 VALU insts/thread removed from pass2. get_bins (pass0)
//      left byte-identical — bin INDICES must match the fp32 reference.
//
// F intermediate stored TRANSPOSED + bf16-packed: FT[ch_img][j][i] (uint32 per
// complex) -> pass2 column loads are contiguous 2KB runs, no cross-wave staging.
//
// Pass 0: transposed bin table binsT[j][i].
// Pass 1: TPB 1024 (16 waves = 16 row-pairs). Wave-private FFT + Hermitian
//         unpack + bf16 pack; ONE barrier; transposed write-out (128B i-runs).
// Pass 2: TPB 256, wave = one column j. bf16 LDS segments.
// Pass 3: reduce 65 tile-partials per batch, normalize, h @ W.T + b.
//
// LAUNCH BOUNDS CALIBRATION (empirical, this toolchain): reported VGPR cap
// ~= 256/arg2 (r3:3->80, r4/6:6->40, r7:8->32, r8:4->56 no-spill). arg2=4 ->
// cap 64.

#define TPB0 256
#define TPB1 1024
#define TPB2 256
#define W2 257
#define NTILE 65           // pass2: 4 columns per block
#define CS 529             // pass1 per-wave segment stride, float2 units
#define CSU (2*CS)         // same stride in uint units (1058)
#define CSB 513            // pass2 per-col segment stride, uint units (==1 mod 32)
#define FTS 512            // FT row stride in uints (2KB rows, line-aligned)
#define PI_F 3.14159265358979323846f
#define TWO_PI_F 6.28318530717958647692f
#define LN2_F 0.69314718055994530942f
#define SB() __builtin_amdgcn_sched_barrier(0)
#define PH(i) ((i) ^ ((((i) >> 6) & 7) * 9))

static constexpr int BR3[8] = {0,4,2,6,1,5,3,7};

__device__ __forceinline__ float2 cmulf(float2 a, float2 b) {
  return make_float2(a.x*b.x - a.y*b.y, a.x*b.y + a.y*b.x);
}
__device__ __forceinline__ float2 cadd(float2 a, float2 b) {
  return make_float2(a.x + b.x, a.y + b.y);
}
__device__ __forceinline__ float2 csub(float2 a, float2 b) {
  return make_float2(a.x - b.x, a.y - b.y);
}
__device__ __forceinline__ float2 cmulnegi(float2 a) {   // a * (-i)
  return make_float2(a.y, -a.x);
}
__device__ __forceinline__ unsigned bfpack(float2 v) {
  unsigned a = __float_as_uint(v.x) >> 16;
  unsigned b = __float_as_uint(v.y) & 0xFFFF0000u;
  return b | a;
}
__device__ __forceinline__ float2 bfunpack(unsigned p) {
  return make_float2(__uint_as_float(p << 16), __uint_as_float(p & 0xFFFF0000u));
}
// exp(2*pi*i*rev) via v_cos/v_sin (hardware takes REVOLUTIONS; |rev|<1 here,
// no reduction needed; ~1ulp, fed into bf16-quantized pipeline).
__device__ __forceinline__ float2 wexp(float rev) {
  return make_float2(__builtin_amdgcn_cosf(rev), __builtin_amdgcn_sinf(rev));
}

// Specialized in-register DIT FFT8. Input bit-rev permuted; output natural.
// Generic radix-2 loop with stage twiddles constant-folded:
// s0: w=1; s1: w in {1,-i}; s2: w in {1, C(1-i), -i, -C(1+i)}, C = sqrt(2)/2.
__device__ __forceinline__ void fft8(float2* z) {
  const float C = 0.70710678118654752f;
  float2 t;
  t = z[1]; z[1] = csub(z[0], t); z[0] = cadd(z[0], t);
  t = z[3]; z[3] = csub(z[2], t); z[2] = cadd(z[2], t);
  t = z[5]; z[5] = csub(z[4], t); z[4] = cadd(z[4], t);
  t = z[7]; z[7] = csub(z[6], t); z[6] = cadd(z[6], t);
  t = z[2];           z[2] = csub(z[0], t); z[0] = cadd(z[0], t);
  t = cmulnegi(z[3]); z[3] = csub(z[1], t); z[1] = cadd(z[1], t);
  t = z[6];           z[6] = csub(z[4], t); z[4] = cadd(z[4], t);
  t = cmulnegi(z[7]); z[7] = csub(z[5], t); z[5] = cadd(z[5], t);
  t = z[4];           z[4] = csub(z[0], t); z[0] = cadd(z[0], t);
  t = make_float2(C * (z[5].x + z[5].y), C * (z[5].y - z[5].x));
                      z[5] = csub(z[1], t); z[1] = cadd(z[1], t);
  t = cmulnegi(z[6]); z[6] = csub(z[2], t); z[2] = cadd(z[2], t);
  t = make_float2(C * (z[7].y - z[7].x), -C * (z[7].x + z[7].y));
                      z[7] = csub(z[3], t); z[3] = cadd(z[3], t);
}

// Apply chained twiddle powers: z[k] *= base^k, k = 1..7.
__device__ __forceinline__ void twiddle_chain(float2* z, float2 base) {
  float2 wk = base;
  #pragma unroll
  for (int k = 1; k < 8; ++k) {
    z[k] = cmulf(z[k], wk);
    if (k < 7) wk = cmulf(wk, base);
  }
}

__device__ __forceinline__ void get_bins(int i, int j, int& rb, int& ob) {
  // EXACT fp32 mirror of the reference — do not substitute fast math here
  // (bin indices flip at boundaries).
  float yy = -1.0f + (float)i * (2.0f / 511.0f);
  float xx = (float)j * (1.0f / 256.0f);
  float rr = sqrtf(yy * yy + xx * xx);
  rr = fminf(rr, 1.0f - 1e-8f);
  float th = atan2f(yy, xx + 1e-9f) + 1.57079632679489662f;
  rb = (int)(rr * 16.0f);
  rb = rb < 0 ? 0 : (rb > 15 ? 15 : rb);
  ob = (int)((th / PI_F) * 8.0f);
  ob = ob < 0 ? 0 : (ob > 7 ? 7 : ob);
}

// Pass 0: TRANSPOSED bin table binsT[j][i] = rb | ob<<4. blockIdx.x = j.
__global__ __launch_bounds__(TPB0) void pass0_kernel(unsigned char* __restrict__ binsT) {
  int j = blockIdx.x;           // 0..256
  #pragma unroll
  for (int e = 0; e < 2; e++) {
    int i = threadIdx.x + e * 256;
    int rb, ob;
    get_bins(i, j, rb, ob);
    binsT[(size_t)j * 512 + i] = (unsigned char)(rb | (ob << 4));
  }
}

// Pass 1: blockIdx.x = ic_local*16 + segblk. Wave wv = row-pair
// rp = segblk*16 + wv (rows 2rp, 2rp+1 packed as one complex 512-pt FFT).
// Output: FT[ic_local][j][i] bf16-packed, i-chunk [segblk*32, +32).
__global__ __launch_bounds__(TPB1, 4) void pass1_kernel(
    const float* __restrict__ x, unsigned* __restrict__ FT, int ic0) {
  __shared__ float2 xbuf[16 * CS];       // 67.7 KB: 16 wave-private segments
  int t = threadIdx.x;
  int segblk = blockIdx.x & 15;
  int ic_local = blockIdx.x >> 4;
  int wv = t >> 6;
  int u = t & 63;
  int rp = segblk * 16 + wv;
  const float* row0 = x + (((size_t)(ic0 + ic_local)) * 512 + (size_t)rp * 2) * 512;
  const float* row1 = row0 + 512;
  float2* seg = xbuf + wv * CS;
  unsigned* useg = (unsigned*)xbuf + wv * CSU;

  const int ul = u & 7, wq = u >> 3;
  const int x9 = 9 * wq, b64 = 64 * wq;

  float2 w1  = wexp((float)u  * (-1.0f / 512.0f));   // W512^-u
  float2 w64 = wexp((float)ul * (-1.0f / 64.0f));    // W64^-ul

  // step 1: FFT8 over m, twiddle W512^(u*k3) via chain
  float2 z[8];
  #pragma unroll
  for (int m = 0; m < 8; ++m)
    z[BR3[m]] = make_float2(row0[u + 64 * m], row1[u + 64 * m]);
  fft8(z);
  twiddle_chain(z, w1);
  SB();
  #pragma unroll
  for (int k3 = 0; k3 < 8; ++k3) seg[(u ^ (9 * k3)) + 64 * k3] = z[k3];   // L1[k3][u]
  SB();
  // step 2: FFT8 over g2, twiddle W64^(ul*K2) via chain
  #pragma unroll
  for (int g2 = 0; g2 < 8; ++g2) z[BR3[g2]] = seg[((ul + 8 * g2) ^ x9) + b64];
  fft8(z);
  twiddle_chain(z, w64);
  SB();
  #pragma unroll
  for (int K2 = 0; K2 < 8; ++K2) seg[((K2 * 8 + ul) ^ x9) + b64] = z[K2]; // L2
  SB();
  // step 3: FFT8 over g1 -> Z[wq + 8ul + 64K1]
  #pragma unroll
  for (int gg = 0; gg < 8; ++gg) z[BR3[gg]] = seg[((ul * 8 + gg) ^ x9) + b64];
  fft8(z);
  SB();
  #pragma unroll
  for (int K1 = 0; K1 < 8; ++K1)
    seg[((wq + 8 * ul) ^ (9 * K1)) + 64 * K1] = z[K1];                    // Z natural, swizzled
  SB();
  // Hermitian unpack (fp32) + bf16 pack; stash as uints in own segment.
  unsigned p0[4], p1[4];
  #pragma unroll
  for (int e = 0; e < 4; ++e) {
    int k = u + 64 * e;
    int km = (512 - k) & 511;
    float2 zk = seg[PH(k)];
    float2 zm = seg[PH(km)];
    p0[e] = bfpack(make_float2(0.5f * (zk.x + zm.x),  0.5f * (zk.y - zm.y)));
    p1[e] = bfpack(make_float2(0.5f * (zk.y + zm.y), -0.5f * (zk.x - zm.x)));
  }
  unsigned p0n = 0, p1n = 0;
  if (u == 0) {
    float2 zk = seg[PH(256)];            // Nyquist (self-paired)
    p0n = bfpack(make_float2(zk.x, 0.0f));
    p1n = bfpack(make_float2(zk.y, 0.0f));
  }
  SB();
  #pragma unroll
  for (int e = 0; e < 4; ++e) {
    int k = u + 64 * e;
    useg[k] = p0[e];                     // row 2rp   spectrum at [k]
    useg[257 + k] = p1[e];               // row 2rp+1 spectrum at [257+k]
  }
  if (u == 0) { useg[256] = p0n; useg[513] = p1n; }
  __syncthreads();

  // transposed write-out: for each j, 32 consecutive i (128B run).
  unsigned* FTc = FT + (size_t)ic_local * (W2 * FTS);
  int i0 = segblk * 32;
  const unsigned* xb = (const unsigned*)xbuf;
  #pragma unroll
  for (int it = 0; it < 9; ++it) {
    int idx = t + TPB1 * it;
    if (idx < W2 * 32) {
      int j = idx >> 5;
      int il = idx & 31;                 // i_local = 2*pair + hi
      unsigned v = xb[(il >> 1) * CSU + (il & 1) * 257 + j];
      FTc[(size_t)j * FTS + i0 + il] = v;
    }
  }
}

// Pass 2: blockIdx.x = b_local*NTILE + tile. Wave wv owns column j = tile*4+wv.
// Contiguous 2KB column loads; wave-private bf16 FFT; zero staging barriers.
// Channel loop software-pipelined (prefetch regs). HW transcendentals (r17).
__global__ __launch_bounds__(TPB2, 4) void pass2_kernel(
    const unsigned* __restrict__ FT, const unsigned char* __restrict__ binsT,
    float* __restrict__ partial, int b0) {
  __shared__ unsigned xbuf[4 * CSB];     // 8.2 KB: 4 wave-private segments
  __shared__ float hist[128];            // combined bins: rb + 16*ob
  int t = threadIdx.x;
  int tile = blockIdx.x % NTILE;
  int b_local = blockIdx.x / NTILE;
  int wv = t >> 6;
  int u = t & 63;
  int j = tile * 4 + wv;
  bool jvalid = (j < W2);
  unsigned* seg = xbuf + wv * CSB;
  const int ul = u & 7, wq = u >> 3;
  const int x9 = 9 * wq, b64 = 64 * wq;

  if (t < 128) hist[t] = 0.0f;
  __syncthreads();

  if (jvalid) {
    float2 w1  = wexp((float)u  * (-1.0f / 512.0f));
    float2 w64 = wexp((float)ul * (-1.0f / 64.0f));

    float mag[8];
    #pragma unroll
    for (int q = 0; q < 8; ++q) mag[q] = 0.0f;

    const unsigned* col0 = FT + ((size_t)(b_local * 3 + 0) * W2 + j) * FTS;
    const unsigned* col1 = col0 + (size_t)W2 * FTS;
    const unsigned* col2 = col1 + (size_t)W2 * FTS;

    // prefetch channel 0
    unsigned pk[8];
    #pragma unroll
    for (int m = 0; m < 8; ++m) pk[m] = col0[u + 64 * m];

    #pragma unroll
    for (int c = 0; c < 3; ++c) {
      float2 z[8];
      #pragma unroll
      for (int m = 0; m < 8; ++m) z[BR3[m]] = bfunpack(pk[m]);
      // issue next channel's loads NOW — latency hides under the FFT chain
      if (c == 0) {
        #pragma unroll
        for (int m = 0; m < 8; ++m) pk[m] = col1[u + 64 * m];
      } else if (c == 1) {
        #pragma unroll
        for (int m = 0; m < 8; ++m) pk[m] = col2[u + 64 * m];
      }
      fft8(z);
      twiddle_chain(z, w1);
      SB();
      #pragma unroll
      for (int k3 = 0; k3 < 8; ++k3) seg[(u ^ (9 * k3)) + 64 * k3] = bfpack(z[k3]);
      SB();
      #pragma unroll
      for (int g2 = 0; g2 < 8; ++g2) z[BR3[g2]] = bfunpack(seg[((ul + 8 * g2) ^ x9) + b64]);
      fft8(z);
      twiddle_chain(z, w64);
      SB();
      #pragma unroll
      for (int K2 = 0; K2 < 8; ++K2) seg[((K2 * 8 + ul) ^ x9) + b64] = bfpack(z[K2]);
      SB();
      #pragma unroll
      for (int gg = 0; gg < 8; ++gg) z[BR3[gg]] = bfunpack(seg[((ul * 8 + gg) ^ x9) + b64]);
      fft8(z);
      #pragma unroll
      for (int K1 = 0; K1 < 8; ++K1)
        mag[K1] += __builtin_amdgcn_sqrtf(z[K1].x * z[K1].x + z[K1].y * z[K1].y);
      SB();                              // seg reads done before next channel's writes
    }

    const unsigned char* bj = binsT + (size_t)j * 512;
    #pragma unroll
    for (int K1 = 0; K1 < 8; ++K1) {
      int row = wq + 8 * ul + 64 * K1;
      int code = bj[row];                // coalesced 64B run per K1
      // scale: ortho (1/512) * channel mean (1/3) = 1/1536
      // ln(1+x) = log2(1+x)*ln2 via v_log_f32 (~1ulp; bins sum ~1e5 then
      // normalize — absolute error negligible vs 2.77e-3 threshold)
      float m = __builtin_amdgcn_logf(1.0f + mag[K1] * (1.0f / 1536.0f)) * LN2_F;
      atomicAdd(&hist[code], m);
    }
  }
  __syncthreads();

  // fold 128 combined bins -> 16 radial + 8 angular partials
  int b = b0 + b_local;
  if (t < 16) {
    float s = 0.0f;
    #pragma unroll
    for (int ob = 0; ob < 8; ++ob) s += hist[t + 16 * ob];
    partial[((size_t)b * NTILE + tile) * 24 + t] = s;
  } else if (t < 24) {
    float s = 0.0f;
    int ob = t - 16;
    #pragma unroll
    for (int rb = 0; rb < 16; ++rb) s += hist[rb + 16 * ob];
    partial[((size_t)b * NTILE + tile) * 24 + t] = s;
  }
}

// Pass 3: one block per batch. Reduce NTILE partials, normalize, project.
__global__ __launch_bounds__(TPB0) void pass3_kernel(
    const float* __restrict__ partial, const float* __restrict__ W,
    const float* __restrict__ bias, float* __restrict__ out) {
  __shared__ float h[24];
  __shared__ float hn[24];
  int b = blockIdx.x;
  int t = threadIdx.x;
  if (t < 24) {
    float s = 0.0f;
    for (int tile = 0; tile < NTILE; tile++)
      s += partial[((size_t)b * NTILE + tile) * 24 + t];
    h[t] = s;
  }
  __syncthreads();
  if (t == 0) {
    float rs = 0.0f, as = 0.0f;
    for (int k = 0; k < 16; k++) rs += h[k];
    for (int k = 16; k < 24; k++) as += h[k];
    for (int k = 0; k < 16; k++) hn[k] = h[k] / (rs + 1e-6f);
    for (int k = 16; k < 24; k++) hn[k] = h[k] / (as + 1e-6f);
  }
  __syncthreads();
  if (t < 64) {
    float acc = bias[t];
    #pragma unroll
    for (int k = 0; k < 24; k++) acc += hn[k] * W[t * 24 + k];
    out[b * 64 + t] = acc;
  }
}

extern "C" void kernel_launch(void* const* d_in, const int* in_sizes, int n_in,
                              void* d_out, int out_size, void* d_ws, size_t ws_size,
                              hipStream_t stream) {
  const float* x    = (const float*)d_in[0];   // [64,3,512,512]
  const float* W    = (const float*)d_in[1];   // [64,24]
  const float* bias = (const float*)d_in[2];   // [64]
  float* out = (float*)d_out;                  // [64,64]

  // ws layout: tile partials | transposed bin table | bf16 F^T
  const size_t partial_bytes = (size_t)64 * NTILE * 24 * sizeof(float);
  size_t off_bins = (partial_bytes + 255) & ~(size_t)255;
  const size_t bins_bytes = (size_t)W2 * 512;
  size_t off_F = ((off_bins + bins_bytes) + 255) & ~(size_t)255;

  float* partial = (float*)d_ws;
  unsigned char* binsT = (unsigned char*)d_ws + off_bins;
  unsigned* FT = (unsigned*)((char*)d_ws + off_F);

  const size_t per_batch = (size_t)3 * W2 * FTS * sizeof(unsigned);  // 1.58 MB
  size_t avail = ws_size > off_F ? ws_size - off_F : 0;
  int bpc = (int)(avail / per_batch);
  if (bpc < 1) bpc = 1;
  if (bpc > 64) bpc = 64;

  pass0_kernel<<<W2, TPB0, 0, stream>>>(binsT);

  for (int b0 = 0; b0 < 64; b0 += bpc) {
    int nb = (64 - b0) < bpc ? (64 - b0) : bpc;
    pass1_kernel<<<nb * 3 * 16, TPB1, 0, stream>>>(x, FT, b0 * 3);
    pass2_kernel<<<nb * NTILE, TPB2, 0, stream>>>(FT, binsT, partial, b0);
  }
  pass3_kernel<<<64, TPB0, 0, stream>>>(partial, W, bias, out);
}